// Round 9
// baseline (916.957 us; speedup 1.0000x reference)
//
#include <hip/hip_runtime.h>
#include <math.h>

// All tensors fp32. B=256, F=512, H=1024, C=1000.

// ---------------------------------------------------------------------------
// pool_all: ONE dispatch for all pooling (verified R7, ~134 us = read wall).
//   blocks [0, nbb)   : big rows (s1..s4), wave per row, 8-deep unroll
//   blocks [nbb, ...) : rowlen-49 rows (s5 then ff), LDS staging
// ---------------------------------------------------------------------------
struct PoolAll {
    const float* src[4];
    float*       dst[4];
    int n4[4];
    int cum[4];
    float inv[4];
    const float* s5;
    const float* ff;
    float*       dst5;
    float*       dstf;
    int nbb;
    int rows5;
};

__global__ __launch_bounds__(256) void pool_all_kernel(PoolAll S) {
    __shared__ float lds[64 * 49];
    if ((int)blockIdx.x < S.nbb) {
        int gid  = blockIdx.x * 256 + threadIdx.x;
        int wave = gid >> 6;
        int lane = gid & 63;
        if (wave >= S.cum[3]) return;
        int s = 0;
        #pragma unroll
        for (int i = 0; i < 3; ++i) if (wave >= S.cum[i]) s = i + 1;
        int row = wave - (s == 0 ? 0 : S.cum[s - 1]);
        const int n4 = S.n4[s];
        const float4* p4 = (const float4*)(S.src[s]) + (size_t)row * n4;
        float a0 = 0.f, a1 = 0.f, a2 = 0.f, a3 = 0.f;
        float a4 = 0.f, a5 = 0.f, a6 = 0.f, a7 = 0.f;
        int k = lane;
        for (; k + 448 < n4; k += 512) {
            float4 v0 = p4[k];       float4 v1 = p4[k + 64];
            float4 v2 = p4[k + 128]; float4 v3 = p4[k + 192];
            float4 v4 = p4[k + 256]; float4 v5 = p4[k + 320];
            float4 v6 = p4[k + 384]; float4 v7 = p4[k + 448];
            a0 += (v0.x + v0.y) + (v0.z + v0.w);
            a1 += (v1.x + v1.y) + (v1.z + v1.w);
            a2 += (v2.x + v2.y) + (v2.z + v2.w);
            a3 += (v3.x + v3.y) + (v3.z + v3.w);
            a4 += (v4.x + v4.y) + (v4.z + v4.w);
            a5 += (v5.x + v5.y) + (v5.z + v5.w);
            a6 += (v6.x + v6.y) + (v6.z + v6.w);
            a7 += (v7.x + v7.y) + (v7.z + v7.w);
        }
        for (; k + 192 < n4; k += 256) {
            float4 v0 = p4[k];       float4 v1 = p4[k + 64];
            float4 v2 = p4[k + 128]; float4 v3 = p4[k + 192];
            a0 += (v0.x + v0.y) + (v0.z + v0.w);
            a1 += (v1.x + v1.y) + (v1.z + v1.w);
            a2 += (v2.x + v2.y) + (v2.z + v2.w);
            a3 += (v3.x + v3.y) + (v3.z + v3.w);
        }
        for (; k < n4; k += 64) {
            float4 v = p4[k];
            a0 += (v.x + v.y) + (v.z + v.w);
        }
        float acc = ((a0 + a1) + (a2 + a3)) + ((a4 + a5) + (a6 + a7));
        #pragma unroll
        for (int off = 32; off > 0; off >>= 1) acc += __shfl_down(acc, off, 64);
        if (lane == 0) S.dst[s][row] = acc * S.inv[s];
        return;
    }
    const int tid  = threadIdx.x;
    const int row0 = (blockIdx.x - S.nbb) * 64;
    const float* src;
    float* dst;
    int rbase;
    if (row0 < S.rows5) { src = S.s5; dst = S.dst5; rbase = row0; }
    else                { src = S.ff; dst = S.dstf; rbase = row0 - S.rows5; }
    const float4* p4 = (const float4*)(src + (size_t)rbase * 49);
    float4* l4 = (float4*)lds;
    float4 v0 = p4[tid];
    float4 v1 = p4[tid + 256];
    float4 v2 = p4[tid + 512];
    float4 v3;
    const bool t3 = (tid < 784 - 768);
    if (t3) v3 = p4[tid + 768];
    l4[tid]       = v0;
    l4[tid + 256] = v1;
    l4[tid + 512] = v2;
    if (t3) l4[tid + 768] = v3;
    __syncthreads();
    const int r  = tid >> 2;
    const int c0 = tid & 3;
    float s = 0.f;
    #pragma unroll
    for (int c = c0; c < 49; c += 4) s += lds[r * 49 + c];
    s += __shfl_down(s, 2, 64);
    s += __shfl_down(s, 1, 64);
    if (c0 == 0) dst[rbase + r] = s * (1.f / 49.f);
}

// ---------------------------------------------------------------------------
// fc_tile_red: R6's verified LDS-tiled split-K SGEMM (tile 64x64, TK=16,
// 4x4 micro, float4 staging, register prefetch) + LAST-BLOCK fused reduce.
// Each block writes its partial slice Pt[ks][M][N], fences, bumps cnt[tile];
// the block seeing KS-1 re-reads all slices in ASCENDING ks order, adds bias
// (+ReLU), writes Y. Summation order identical to R6's reduce_bias_kernel.
// Graph-capture safe (plain launch, device-scope atomics per G12/G16).
// ---------------------------------------------------------------------------
__global__ __launch_bounds__(256) void fc_tile_red_kernel(
        const float* __restrict__ X, const float* __restrict__ W,
        const float* __restrict__ bias, float* __restrict__ Y,
        float* __restrict__ Pt, int* __restrict__ cnt,
        int M, int K, int N, int Kc, int ntiles, int do_relu) {
    __shared__ __align__(16) float Xs[16][68];   // [k][m]
    __shared__ __align__(16) float Ws[16][68];   // [k][n]
    __shared__ int s_old;
    const int tpk = 4 * ntiles;            // mtiles=4
    const int bid = blockIdx.x;
    const int ks  = bid / tpk;
    const int rem = bid - ks * tpk;        // tile id within layer
    const int mt  = rem / ntiles;
    const int nt  = rem - mt * ntiles;
    const int m0 = mt * 64, n0 = nt * 64;
    const int k0 = ks * Kc;
    int k1 = k0 + Kc; if (k1 > K) k1 = K;
    const int KS = (K + Kc - 1) / Kc;
    const int MN = M * N;

    const int tid = threadIdx.x;
    const int tm = tid & 15;
    const int tn = tid >> 4;
    const int xr = tid >> 2, xc = tid & 3;
    const int wr = tid >> 4, wc = tid & 15;
    const int nwc = n0 + wc * 4;

    float4 acc[4];
    #pragma unroll
    for (int r = 0; r < 4; ++r) acc[r] = make_float4(0.f, 0.f, 0.f, 0.f);

    float4 xv, wv;
    xv = *(const float4*)(X + (size_t)(m0 + xr) * K + k0 + xc * 4);
    if (nwc + 3 < N) {
        wv = *(const float4*)(W + (size_t)(k0 + wr) * N + nwc);
    } else {
        wv.x = (nwc + 0 < N) ? W[(size_t)(k0 + wr) * N + nwc + 0] : 0.f;
        wv.y = (nwc + 1 < N) ? W[(size_t)(k0 + wr) * N + nwc + 1] : 0.f;
        wv.z = (nwc + 2 < N) ? W[(size_t)(k0 + wr) * N + nwc + 2] : 0.f;
        wv.w = (nwc + 3 < N) ? W[(size_t)(k0 + wr) * N + nwc + 3] : 0.f;
    }

    for (int kt = k0; kt < k1; kt += 16) {
        __syncthreads();
        Xs[xc * 4 + 0][xr] = xv.x;
        Xs[xc * 4 + 1][xr] = xv.y;
        Xs[xc * 4 + 2][xr] = xv.z;
        Xs[xc * 4 + 3][xr] = xv.w;
        *(float4*)&Ws[wr][wc * 4] = wv;
        __syncthreads();
        if (kt + 16 < k1) {
            xv = *(const float4*)(X + (size_t)(m0 + xr) * K + kt + 16 + xc * 4);
            if (nwc + 3 < N) {
                wv = *(const float4*)(W + (size_t)(kt + 16 + wr) * N + nwc);
            } else {
                wv.x = (nwc + 0 < N) ? W[(size_t)(kt + 16 + wr) * N + nwc + 0] : 0.f;
                wv.y = (nwc + 1 < N) ? W[(size_t)(kt + 16 + wr) * N + nwc + 1] : 0.f;
                wv.z = (nwc + 2 < N) ? W[(size_t)(kt + 16 + wr) * N + nwc + 2] : 0.f;
                wv.w = (nwc + 3 < N) ? W[(size_t)(kt + 16 + wr) * N + nwc + 3] : 0.f;
            }
        }
        #pragma unroll
        for (int kk = 0; kk < 16; ++kk) {
            float4 xr4 = *(const float4*)&Xs[kk][tm * 4];
            float4 wr4 = *(const float4*)&Ws[kk][tn * 4];
            acc[0].x += xr4.x * wr4.x; acc[0].y += xr4.x * wr4.y;
            acc[0].z += xr4.x * wr4.z; acc[0].w += xr4.x * wr4.w;
            acc[1].x += xr4.y * wr4.x; acc[1].y += xr4.y * wr4.y;
            acc[1].z += xr4.y * wr4.z; acc[1].w += xr4.y * wr4.w;
            acc[2].x += xr4.z * wr4.x; acc[2].y += xr4.z * wr4.y;
            acc[2].z += xr4.z * wr4.z; acc[2].w += xr4.z * wr4.w;
            acc[3].x += xr4.w * wr4.x; acc[3].y += xr4.w * wr4.y;
            acc[3].z += xr4.w * wr4.z; acc[3].w += xr4.w * wr4.w;
        }
    }

    // write this slice's partials
    const int nbase = n0 + tn * 4;
    #pragma unroll
    for (int r = 0; r < 4; ++r) {
        int row = m0 + tm * 4 + r;
        float* pp = Pt + (size_t)ks * MN + (size_t)row * N + nbase;
        if (nbase + 3 < N) {
            *(float4*)pp = acc[r];
        } else {
            float vv[4] = { acc[r].x, acc[r].y, acc[r].z, acc[r].w };
            for (int c = 0; c < 4; ++c) if (nbase + c < N) pp[c] = vv[c];
        }
    }

    // release: make partials visible, then bump the tile counter
    __threadfence();
    __syncthreads();
    if (tid == 0) s_old = atomicAdd(&cnt[rem], 1);
    __syncthreads();
    if (s_old != KS - 1) return;
    __threadfence();                       // acquire: see all slices

    // deterministic reduce (ks ascending) + bias (+relu) -> Y
    #pragma unroll
    for (int r = 0; r < 4; ++r) {
        int row = m0 + tm * 4 + r;
        const float* pp = Pt + (size_t)row * N + nbase;
        if (nbase + 3 < N) {
            float4 a = *(const float4*)pp;
            for (int s = 1; s < KS; ++s) {
                float4 b = *(const float4*)(pp + (size_t)s * MN);
                a.x += b.x; a.y += b.y; a.z += b.z; a.w += b.w;
            }
            float4 bb = *(const float4*)(bias + nbase);
            a.x += bb.x; a.y += bb.y; a.z += bb.z; a.w += bb.w;
            if (do_relu) {
                a.x = fmaxf(a.x, 0.f); a.y = fmaxf(a.y, 0.f);
                a.z = fmaxf(a.z, 0.f); a.w = fmaxf(a.w, 0.f);
            }
            *(float4*)(Y + (size_t)row * N + nbase) = a;
        } else {
            for (int c = 0; c < 4; ++c) {
                int n = nbase + c;
                if (n < N) {
                    float a = pp[c];
                    for (int s = 1; s < KS; ++s) a += pp[c + (size_t)s * MN];
                    a += bias[n];
                    if (do_relu) a = fmaxf(a, 0.f);
                    Y[(size_t)row * N + n] = a;
                }
            }
        }
    }
}

// ---------------------------------------------------------------------------
// fc3 + proj in ONE dispatch (independent work, block-range split).
//   blocks [0,256)   : gate fc3 (K=512 -> 5 logits) + top-2 + softmax
//   blocks [256,416) : batched projection GEMM (5 stages x 32 tiles, TK=8)
// jax.lax.top_k tie rule: lower index wins on equality (strict >).
// ---------------------------------------------------------------------------
struct ProjParams {
    const float* W[5];
    const float* bp[5];
    const float* g[5];
    const float* be[5];
    int K[5];
    int poff[5];
};

__global__ __launch_bounds__(256) void fc3_proj_kernel(
        const float* __restrict__ Xg, const float* __restrict__ Wg3,
        const float* __restrict__ bg3, int* __restrict__ topi,
        float* __restrict__ wsm, float* __restrict__ out_gl,
        float* __restrict__ out_topi, float* __restrict__ out_w,
        ProjParams P, const float* __restrict__ pools,
        float* __restrict__ proj_out) {
    __shared__ __align__(16) float Xs[8][68];
    __shared__ __align__(16) float Ws[8][68];
    __shared__ float red[4][5];
    const int tid = threadIdx.x;

    if (blockIdx.x < 256) {
        // ---- fc3 + top2 ----
        const int b    = blockIdx.x;
        const int lane = tid & 63;
        const int wv   = tid >> 6;
        const float* x = Xg + (size_t)b * 512;
        float acc[5] = {0.f, 0.f, 0.f, 0.f, 0.f};
        for (int k = tid; k < 512; k += 256) {
            float xv = x[k];
            const float* wr = Wg3 + (size_t)k * 5;
            acc[0] += xv * wr[0]; acc[1] += xv * wr[1]; acc[2] += xv * wr[2];
            acc[3] += xv * wr[3]; acc[4] += xv * wr[4];
        }
        #pragma unroll
        for (int off = 32; off > 0; off >>= 1) {
            #pragma unroll
            for (int j = 0; j < 5; ++j) acc[j] += __shfl_down(acc[j], off, 64);
        }
        if (lane == 0) {
            #pragma unroll
            for (int j = 0; j < 5; ++j) red[wv][j] = acc[j];
        }
        __syncthreads();
        if (tid == 0) {
            float v[5];
            #pragma unroll
            for (int j = 0; j < 5; ++j)
                v[j] = ((red[0][j] + red[1][j]) + (red[2][j] + red[3][j])) + bg3[j];
            int i0 = 0;
            #pragma unroll
            for (int i = 1; i < 5; ++i) if (v[i] > v[i0]) i0 = i;
            int i1 = -1;
            #pragma unroll
            for (int i = 0; i < 5; ++i) {
                if (i == i0) continue;
                if (i1 < 0 || v[i] > v[i1]) i1 = i;
            }
            float e1 = __expf(v[i1] - v[i0]);
            float inv = 1.f / (1.f + e1);
            float w0 = inv, w1 = e1 * inv;
            topi[b * 2] = i0; topi[b * 2 + 1] = i1;
            wsm[b * 2] = w0;  wsm[b * 2 + 1] = w1;
            #pragma unroll
            for (int j = 0; j < 5; ++j) out_gl[b * 5 + j] = v[j];
            out_topi[b * 2]     = (float)i0;
            out_topi[b * 2 + 1] = (float)i1;
            out_w[b * 2]     = w0;
            out_w[b * 2 + 1] = w1;
        }
        return;
    }

    // ---- projection GEMM task ----
    const int task = blockIdx.x - 256;     // 0..159
    const int st  = task >> 5;
    const int bid = task & 31;
    const int K  = P.K[st];
    const float* X = pools + P.poff[st];
    const float* W = P.W[st];
    const int N = 512;
    int mt  = bid >> 3;
    int nt  = bid & 7;
    const int m0 = mt * 64, n0 = nt * 64;

    const int tm = tid & 15;
    const int tn = tid >> 4;
    const int xa = tid >> 3, xb = tid & 7;
    const int wc = tid & 63, wb = tid >> 6;
    const int nw = n0 + wc;

    float4 acc[4];
    #pragma unroll
    for (int r = 0; r < 4; ++r) acc[r] = make_float4(0.f, 0.f, 0.f, 0.f);

    float x0, x1, w0v, w1v;
    x0  = X[(size_t)(m0 + xa) * K + xb];
    x1  = X[(size_t)(m0 + xa + 32) * K + xb];
    w0v = W[(size_t)wb * N + nw];
    w1v = W[(size_t)(wb + 4) * N + nw];

    for (int kt = 0; kt < K; kt += 8) {
        __syncthreads();
        Xs[xb][xa] = x0; Xs[xb][xa + 32] = x1;
        Ws[wb][wc] = w0v; Ws[wb + 4][wc] = w1v;
        __syncthreads();
        if (kt + 8 < K) {
            x0  = X[(size_t)(m0 + xa) * K + kt + 8 + xb];
            x1  = X[(size_t)(m0 + xa + 32) * K + kt + 8 + xb];
            w0v = W[(size_t)(kt + 8 + wb) * N + nw];
            w1v = W[(size_t)(kt + 8 + wb + 4) * N + nw];
        }
        #pragma unroll
        for (int kk = 0; kk < 8; ++kk) {
            float4 xr = *(const float4*)&Xs[kk][tm * 4];
            float4 wr = *(const float4*)&Ws[kk][tn * 4];
            acc[0].x += xr.x * wr.x; acc[0].y += xr.x * wr.y;
            acc[0].z += xr.x * wr.z; acc[0].w += xr.x * wr.w;
            acc[1].x += xr.y * wr.x; acc[1].y += xr.y * wr.y;
            acc[1].z += xr.y * wr.z; acc[1].w += xr.y * wr.w;
            acc[2].x += xr.z * wr.x; acc[2].y += xr.z * wr.y;
            acc[2].z += xr.z * wr.z; acc[2].w += xr.z * wr.w;
            acc[3].x += xr.w * wr.x; acc[3].y += xr.w * wr.y;
            acc[3].z += xr.w * wr.z; acc[3].w += xr.w * wr.w;
        }
    }
    const int nbase = n0 + tn * 4;
    float4 bb = *(const float4*)(P.bp[st] + nbase);
    float* op = proj_out + (size_t)st * 131072 + (size_t)(m0 + tm * 4) * N + nbase;
    #pragma unroll
    for (int r = 0; r < 4; ++r) {
        float4 v = acc[r];
        v.x += bb.x; v.y += bb.y; v.z += bb.z; v.w += bb.w;
        *(float4*)(op + (size_t)r * N) = v;
    }
}

// ---------------------------------------------------------------------------
// mixln: gather the two selected projections per batch, LayerNorm + exact
// GELU + softmax-weighted sum. One block of 512 per batch (verified R6).
// ---------------------------------------------------------------------------
__global__ __launch_bounds__(512) void mixln_kernel(ProjParams P,
        const float* __restrict__ proj_out, const int* __restrict__ topi,
        const float* __restrict__ wsm, float* __restrict__ mix) {
    const int b = blockIdx.x;
    const int f = threadIdx.x;           // 0..511
    __shared__ float redS[8], redQ[8];
    __shared__ float s_mu, s_rstd;

    float acc = 0.f;
    for (int j = 0; j < 2; ++j) {
        __syncthreads();
        const int st = topi[b * 2 + j];
        float h = proj_out[(size_t)st * 131072 + (size_t)b * 512 + f];

        float s = h, q = h * h;
        #pragma unroll
        for (int off = 32; off > 0; off >>= 1) {
            s += __shfl_down(s, off, 64);
            q += __shfl_down(q, off, 64);
        }
        const int lane = threadIdx.x & 63, wid = threadIdx.x >> 6;
        if (lane == 0) { redS[wid] = s; redQ[wid] = q; }
        __syncthreads();
        if (threadIdx.x == 0) {
            float ts = 0.f, tq = 0.f;
            #pragma unroll
            for (int i = 0; i < 8; ++i) { ts += redS[i]; tq += redQ[i]; }
            float mu  = ts * (1.f / 512.f);
            float var = tq * (1.f / 512.f) - mu * mu;
            s_mu   = mu;
            s_rstd = rsqrtf(var + 1e-5f);
        }
        __syncthreads();

        float x  = (h - s_mu) * s_rstd * P.g[st][f] + P.be[st][f];
        float ge = 0.5f * x * (1.f + erff(x * 0.70710678118654752f));
        acc += wsm[b * 2 + j] * ge;
    }
    mix[(size_t)b * 512 + f] = acc;
}

// ---------------------------------------------------------------------------
extern "C" void kernel_launch(void* const* d_in, const int* in_sizes, int n_in,
                              void* d_out, int out_size, void* d_ws, size_t ws_size,
                              hipStream_t stream) {
    const int B = 256;

    const float* s1 = (const float*)d_in[0];
    const float* s2 = (const float*)d_in[1];
    const float* s3 = (const float*)d_in[2];
    const float* s4 = (const float*)d_in[3];
    const float* s5 = (const float*)d_in[4];
    const float* ff = (const float*)d_in[5];
    const float *Wp[5], *bp[5], *g[5], *be[5];
    for (int i = 0; i < 5; ++i) {
        Wp[i] = (const float*)d_in[6 + 4 * i];
        bp[i] = (const float*)d_in[7 + 4 * i];
        g[i]  = (const float*)d_in[8 + 4 * i];
        be[i] = (const float*)d_in[9 + 4 * i];
    }
    const float* Wg1 = (const float*)d_in[26]; const float* bg1 = (const float*)d_in[27];
    const float* Wg2 = (const float*)d_in[28]; const float* bg2 = (const float*)d_in[29];
    const float* Wg3 = (const float*)d_in[30]; const float* bg3 = (const float*)d_in[31];
    const float* Wc1 = (const float*)d_in[32]; const float* bc1 = (const float*)d_in[33];
    const float* Wc2 = (const float*)d_in[34]; const float* bc2 = (const float*)d_in[35];
    const float* Wc3 = (const float*)d_in[36]; const float* bc3 = (const float*)d_in[37];

    // ---- workspace layout (fp32 elements) ----
    float* ws = (float*)d_ws;
    const int Ks[5]   = {16, 24, 40, 80, 160};
    const int poff[5] = {0, 4096, 10240, 20480, 40960};
    float* pools    = ws;                                     // 81920
    float* gate_in  = ws + 81920;                             // 245760
    float* g1h      = ws + 327680;                            // 262144
    float* g2h      = ws + 589824;                            // 131072
    float* wsm      = ws + 720896;                            // 512
    int*   topi     = (int*)(ws + 721408);                    // 512
    float* mix      = ws + 721920;                            // 131072
    float* proj_out = ws + 852992;                            // 655360
    float* c1h      = ws + 1508352;                           // 262144
    float* c2h      = ws + 1770496;                           // 131072
    int*   cnt      = (int*)(ws + 1901568);                   // 256 ints
    float* slab     = ws + 1901824;                           // 2097152

    float* out      = (float*)d_out;
    float* out_gl   = out + 256000;
    float* out_topi = out + 257280;
    float* out_w    = out + 257792;

    // ---- 0) zero the split-K tile counters (ws is poisoned each iter) ----
    hipMemsetAsync(cnt, 0, 256 * sizeof(int), stream);

    // ---- 1) ALL pooling in one dispatch ----
    {
        PoolAll S;
        const float* srcs[4] = { s1, s2, s3, s4 };
        const int rls[4]  = { 112 * 112, 56 * 56, 28 * 28, 14 * 14 };
        const int rows[4] = { B * 16, B * 24, B * 40, B * 80 };
        int cum = 0;
        for (int i = 0; i < 4; ++i) {
            S.src[i] = srcs[i]; S.dst[i] = pools + poff[i]; S.n4[i] = rls[i] / 4;
            cum += rows[i]; S.cum[i] = cum; S.inv[i] = 1.f / rls[i];
        }
        S.nbb   = (cum * 64) / 256;           // 10240
        S.s5    = s5; S.ff = ff;
        S.dst5  = pools + poff[4]; S.dstf = gate_in;
        S.rows5 = B * 160;
        int small_blocks = (S.rows5 + B * 960) / 64;   // 4480
        pool_all_kernel<<<S.nbb + small_blocks, 256, 0, stream>>>(S);
    }

    // ---- 2) gate MLP: 1 dispatch per layer (fused split-K reduce) ----
    // gate1: [256,960]x[960,1024], KS=8 (Kc=128), tiles=64, counters cnt+0
    fc_tile_red_kernel<<<8 * 4 * 16, 256, 0, stream>>>(
        gate_in, Wg1, bg1, g1h, slab, cnt + 0, 256, 960, 1024, 128, 16, 1);
    // gate2: [256,1024]x[1024,512], KS=16 (Kc=64), tiles=32, counters cnt+64
    fc_tile_red_kernel<<<16 * 4 * 8, 256, 0, stream>>>(
        g1h, Wg2, bg2, g2h, slab, cnt + 64, 256, 1024, 512, 64, 8, 1);

    // ---- 3) fc3+top2 || all 5 projections, then mixln ----
    ProjParams P;
    for (int i = 0; i < 5; ++i) {
        P.W[i] = Wp[i]; P.bp[i] = bp[i]; P.g[i] = g[i]; P.be[i] = be[i];
        P.K[i] = Ks[i]; P.poff[i] = poff[i];
    }
    fc3_proj_kernel<<<416, 256, 0, stream>>>(g2h, Wg3, bg3, topi, wsm,
                                             out_gl, out_topi, out_w,
                                             P, pools, proj_out);
    mixln_kernel<<<B, 512, 0, stream>>>(P, proj_out, topi, wsm, mix);

    // ---- 4) classifier MLP: 1 dispatch per layer ----
    // cls1: [256,512]x[512,1024], KS=8 (Kc=64), tiles=64, counters cnt+96
    fc_tile_red_kernel<<<8 * 4 * 16, 256, 0, stream>>>(
        mix, Wc1, bc1, c1h, slab, cnt + 96, 256, 512, 1024, 64, 16, 1);
    // cls2: [256,1024]x[1024,512], KS=16 (Kc=64), tiles=32, counters cnt+160
    fc_tile_red_kernel<<<16 * 4 * 8, 256, 0, stream>>>(
        c1h, Wc2, bc2, c2h, slab, cnt + 160, 256, 1024, 512, 64, 8, 1);
    // cls3: [256,512]x[512,1000], KS=8 (Kc=64), tiles=64, counters cnt+192
    fc_tile_red_kernel<<<8 * 4 * 16, 256, 0, stream>>>(
        c2h, Wc3, bc3, out, slab, cnt + 192, 256, 512, 1000, 64, 16, 0);
}

// Round 10
// 714.693 us; speedup vs baseline: 1.2830x; 1.2830x over previous
//
#include <hip/hip_runtime.h>
#include <math.h>

// All tensors fp32. B=256, F=512, H=1024, C=1000.

// ---------------------------------------------------------------------------
// pool_all: ONE dispatch for all pooling (verified R7/R9, ~134 us read wall).
// ---------------------------------------------------------------------------
struct PoolAll {
    const float* src[4];
    float*       dst[4];
    int n4[4];
    int cum[4];
    float inv[4];
    const float* s5;
    const float* ff;
    float*       dst5;
    float*       dstf;
    int nbb;
    int rows5;
};

__global__ __launch_bounds__(256) void pool_all_kernel(PoolAll S) {
    __shared__ float lds[64 * 49];
    if ((int)blockIdx.x < S.nbb) {
        int gid  = blockIdx.x * 256 + threadIdx.x;
        int wave = gid >> 6;
        int lane = gid & 63;
        if (wave >= S.cum[3]) return;
        int s = 0;
        #pragma unroll
        for (int i = 0; i < 3; ++i) if (wave >= S.cum[i]) s = i + 1;
        int row = wave - (s == 0 ? 0 : S.cum[s - 1]);
        const int n4 = S.n4[s];
        const float4* p4 = (const float4*)(S.src[s]) + (size_t)row * n4;
        float a0 = 0.f, a1 = 0.f, a2 = 0.f, a3 = 0.f;
        float a4 = 0.f, a5 = 0.f, a6 = 0.f, a7 = 0.f;
        int k = lane;
        for (; k + 448 < n4; k += 512) {
            float4 v0 = p4[k];       float4 v1 = p4[k + 64];
            float4 v2 = p4[k + 128]; float4 v3 = p4[k + 192];
            float4 v4 = p4[k + 256]; float4 v5 = p4[k + 320];
            float4 v6 = p4[k + 384]; float4 v7 = p4[k + 448];
            a0 += (v0.x + v0.y) + (v0.z + v0.w);
            a1 += (v1.x + v1.y) + (v1.z + v1.w);
            a2 += (v2.x + v2.y) + (v2.z + v2.w);
            a3 += (v3.x + v3.y) + (v3.z + v3.w);
            a4 += (v4.x + v4.y) + (v4.z + v4.w);
            a5 += (v5.x + v5.y) + (v5.z + v5.w);
            a6 += (v6.x + v6.y) + (v6.z + v6.w);
            a7 += (v7.x + v7.y) + (v7.z + v7.w);
        }
        for (; k + 192 < n4; k += 256) {
            float4 v0 = p4[k];       float4 v1 = p4[k + 64];
            float4 v2 = p4[k + 128]; float4 v3 = p4[k + 192];
            a0 += (v0.x + v0.y) + (v0.z + v0.w);
            a1 += (v1.x + v1.y) + (v1.z + v1.w);
            a2 += (v2.x + v2.y) + (v2.z + v2.w);
            a3 += (v3.x + v3.y) + (v3.z + v3.w);
        }
        for (; k < n4; k += 64) {
            float4 v = p4[k];
            a0 += (v.x + v.y) + (v.z + v.w);
        }
        float acc = ((a0 + a1) + (a2 + a3)) + ((a4 + a5) + (a6 + a7));
        #pragma unroll
        for (int off = 32; off > 0; off >>= 1) acc += __shfl_down(acc, off, 64);
        if (lane == 0) S.dst[s][row] = acc * S.inv[s];
        return;
    }
    const int tid  = threadIdx.x;
    const int row0 = (blockIdx.x - S.nbb) * 64;
    const float* src;
    float* dst;
    int rbase;
    if (row0 < S.rows5) { src = S.s5; dst = S.dst5; rbase = row0; }
    else                { src = S.ff; dst = S.dstf; rbase = row0 - S.rows5; }
    const float4* p4 = (const float4*)(src + (size_t)rbase * 49);
    float4* l4 = (float4*)lds;
    float4 v0 = p4[tid];
    float4 v1 = p4[tid + 256];
    float4 v2 = p4[tid + 512];
    float4 v3;
    const bool t3 = (tid < 784 - 768);
    if (t3) v3 = p4[tid + 768];
    l4[tid]       = v0;
    l4[tid + 256] = v1;
    l4[tid + 512] = v2;
    if (t3) l4[tid + 768] = v3;
    __syncthreads();
    const int r  = tid >> 2;
    const int c0 = tid & 3;
    float s = 0.f;
    #pragma unroll
    for (int c = c0; c < 49; c += 4) s += lds[r * 49 + c];
    s += __shfl_down(s, 2, 64);
    s += __shfl_down(s, 1, 64);
    if (c0 == 0) dst[rbase + r] = s * (1.f / 49.f);
}

// ---------------------------------------------------------------------------
// fc_body: KS=1 LDS-tiled SGEMM layer (tile 64x64, TK=16, 4x4 micro, float4
// staging, register prefetch — the R6-verified tile code) with bias (+ReLU)
// epilogue (R7-verified). One dispatch per layer, no partials, no reduce.
// M=256 fixed (mtiles=4). K % 16 == 0. N arbitrary (masked).
// ---------------------------------------------------------------------------
__device__ void fc_body(const float* __restrict__ X, const float* __restrict__ W,
        const float* __restrict__ bias, float* __restrict__ Y,
        int K, int N, int ntiles, int tile, int do_relu,
        float (*Xs)[68], float (*Ws)[68]) {
    const int mt = tile / ntiles;
    const int nt = tile - mt * ntiles;
    const int m0 = mt * 64, n0 = nt * 64;

    const int tid = threadIdx.x;
    const int tm = tid & 15;
    const int tn = tid >> 4;
    const int xr = tid >> 2, xc = tid & 3;
    const int wr = tid >> 4, wc = tid & 15;
    const int nwc = n0 + wc * 4;

    float4 acc[4];
    #pragma unroll
    for (int r = 0; r < 4; ++r) acc[r] = make_float4(0.f, 0.f, 0.f, 0.f);

    float4 xv, wv;
    xv = *(const float4*)(X + (size_t)(m0 + xr) * K + xc * 4);
    if (nwc + 3 < N) {
        wv = *(const float4*)(W + (size_t)wr * N + nwc);
    } else {
        wv.x = (nwc + 0 < N) ? W[(size_t)wr * N + nwc + 0] : 0.f;
        wv.y = (nwc + 1 < N) ? W[(size_t)wr * N + nwc + 1] : 0.f;
        wv.z = (nwc + 2 < N) ? W[(size_t)wr * N + nwc + 2] : 0.f;
        wv.w = (nwc + 3 < N) ? W[(size_t)wr * N + nwc + 3] : 0.f;
    }

    for (int kt = 0; kt < K; kt += 16) {
        __syncthreads();
        Xs[xc * 4 + 0][xr] = xv.x;
        Xs[xc * 4 + 1][xr] = xv.y;
        Xs[xc * 4 + 2][xr] = xv.z;
        Xs[xc * 4 + 3][xr] = xv.w;
        *(float4*)&Ws[wr][wc * 4] = wv;
        __syncthreads();
        if (kt + 16 < K) {
            xv = *(const float4*)(X + (size_t)(m0 + xr) * K + kt + 16 + xc * 4);
            if (nwc + 3 < N) {
                wv = *(const float4*)(W + (size_t)(kt + 16 + wr) * N + nwc);
            } else {
                wv.x = (nwc + 0 < N) ? W[(size_t)(kt + 16 + wr) * N + nwc + 0] : 0.f;
                wv.y = (nwc + 1 < N) ? W[(size_t)(kt + 16 + wr) * N + nwc + 1] : 0.f;
                wv.z = (nwc + 2 < N) ? W[(size_t)(kt + 16 + wr) * N + nwc + 2] : 0.f;
                wv.w = (nwc + 3 < N) ? W[(size_t)(kt + 16 + wr) * N + nwc + 3] : 0.f;
            }
        }
        #pragma unroll
        for (int kk = 0; kk < 16; ++kk) {
            float4 xr4 = *(const float4*)&Xs[kk][tm * 4];
            float4 wr4 = *(const float4*)&Ws[kk][tn * 4];
            acc[0].x += xr4.x * wr4.x; acc[0].y += xr4.x * wr4.y;
            acc[0].z += xr4.x * wr4.z; acc[0].w += xr4.x * wr4.w;
            acc[1].x += xr4.y * wr4.x; acc[1].y += xr4.y * wr4.y;
            acc[1].z += xr4.y * wr4.z; acc[1].w += xr4.y * wr4.w;
            acc[2].x += xr4.z * wr4.x; acc[2].y += xr4.z * wr4.y;
            acc[2].z += xr4.z * wr4.z; acc[2].w += xr4.z * wr4.w;
            acc[3].x += xr4.w * wr4.x; acc[3].y += xr4.w * wr4.y;
            acc[3].z += xr4.w * wr4.z; acc[3].w += xr4.w * wr4.w;
        }
    }
    const int nbase = n0 + tn * 4;
    #pragma unroll
    for (int r = 0; r < 4; ++r) {
        int row = m0 + tm * 4 + r;
        float* yp = Y + (size_t)row * N + nbase;
        if (nbase + 3 < N) {
            float4 bb = *(const float4*)(bias + nbase);
            float4 v = acc[r];
            v.x += bb.x; v.y += bb.y; v.z += bb.z; v.w += bb.w;
            if (do_relu) {
                v.x = fmaxf(v.x, 0.f); v.y = fmaxf(v.y, 0.f);
                v.z = fmaxf(v.z, 0.f); v.w = fmaxf(v.w, 0.f);
            }
            *(float4*)yp = v;
        } else {
            float vv[4] = { acc[r].x, acc[r].y, acc[r].z, acc[r].w };
            for (int c = 0; c < 4; ++c) {
                int n = nbase + c;
                if (n < N) {
                    float v = vv[c] + bias[n];
                    if (do_relu) v = fmaxf(v, 0.f);
                    yp[c] = v;
                }
            }
        }
    }
}

__global__ __launch_bounds__(256) void fc_plain_kernel(const float* __restrict__ X,
        const float* __restrict__ W, const float* __restrict__ bias,
        float* __restrict__ Y, int K, int N, int ntiles, int do_relu) {
    __shared__ __align__(16) float Xs[16][68];
    __shared__ __align__(16) float Ws[16][68];
    fc_body(X, W, bias, Y, K, N, ntiles, blockIdx.x, do_relu, Xs, Ws);
}

// ---------------------------------------------------------------------------
// proj_body: batched projection GEMM task (TK=8, verified R6/R9). One task =
// (stage, 64x64 tile); 5 stages x 32 tiles = 160 tasks. Bias fused.
// ---------------------------------------------------------------------------
struct ProjParams {
    const float* W[5];
    const float* bp[5];
    const float* g[5];
    const float* be[5];
    int K[5];
    int poff[5];
};

__device__ void proj_body(const ProjParams& P, const float* __restrict__ pools,
        float* __restrict__ proj_out, int task,
        float (*Xs)[68], float (*Ws)[68]) {
    const int st  = task >> 5;
    const int bid = task & 31;
    const int K  = P.K[st];
    const float* X = pools + P.poff[st];
    const float* W = P.W[st];
    const int N = 512;
    int mt  = bid >> 3;
    int nt  = bid & 7;
    const int m0 = mt * 64, n0 = nt * 64;

    const int tid = threadIdx.x;
    const int tm = tid & 15;
    const int tn = tid >> 4;
    const int xa = tid >> 3, xb = tid & 7;
    const int wc = tid & 63, wb = tid >> 6;
    const int nw = n0 + wc;

    float4 acc[4];
    #pragma unroll
    for (int r = 0; r < 4; ++r) acc[r] = make_float4(0.f, 0.f, 0.f, 0.f);

    float x0, x1, w0v, w1v;
    x0  = X[(size_t)(m0 + xa) * K + xb];
    x1  = X[(size_t)(m0 + xa + 32) * K + xb];
    w0v = W[(size_t)wb * N + nw];
    w1v = W[(size_t)(wb + 4) * N + nw];

    for (int kt = 0; kt < K; kt += 8) {
        __syncthreads();
        Xs[xb][xa] = x0; Xs[xb][xa + 32] = x1;
        Ws[wb][wc] = w0v; Ws[wb + 4][wc] = w1v;
        __syncthreads();
        if (kt + 8 < K) {
            x0  = X[(size_t)(m0 + xa) * K + kt + 8 + xb];
            x1  = X[(size_t)(m0 + xa + 32) * K + kt + 8 + xb];
            w0v = W[(size_t)(kt + 8 + wb) * N + nw];
            w1v = W[(size_t)(kt + 8 + wb + 4) * N + nw];
        }
        #pragma unroll
        for (int kk = 0; kk < 8; ++kk) {
            float4 xr = *(const float4*)&Xs[kk][tm * 4];
            float4 wr = *(const float4*)&Ws[kk][tn * 4];
            acc[0].x += xr.x * wr.x; acc[0].y += xr.x * wr.y;
            acc[0].z += xr.x * wr.z; acc[0].w += xr.x * wr.w;
            acc[1].x += xr.y * wr.x; acc[1].y += xr.y * wr.y;
            acc[1].z += xr.y * wr.z; acc[1].w += xr.y * wr.w;
            acc[2].x += xr.z * wr.x; acc[2].y += xr.z * wr.y;
            acc[2].z += xr.z * wr.z; acc[2].w += xr.z * wr.w;
            acc[3].x += xr.w * wr.x; acc[3].y += xr.w * wr.y;
            acc[3].z += xr.w * wr.z; acc[3].w += xr.w * wr.w;
        }
    }
    const int nbase = n0 + tn * 4;
    float4 bb = *(const float4*)(P.bp[st] + nbase);
    float* op = proj_out + (size_t)st * 131072 + (size_t)(m0 + tm * 4) * N + nbase;
    #pragma unroll
    for (int r = 0; r < 4; ++r) {
        float4 v = acc[r];
        v.x += bb.x; v.y += bb.y; v.z += bb.z; v.w += bb.w;
        *(float4*)(op + (size_t)r * N) = v;
    }
}

// gate1 (64 tiles) + proj (160 tasks) in ONE dispatch — independent work.
__global__ __launch_bounds__(256) void gate1_proj_kernel(
        const float* __restrict__ gate_in, const float* __restrict__ Wg1,
        const float* __restrict__ bg1, float* __restrict__ g1h,
        ProjParams P, const float* __restrict__ pools,
        float* __restrict__ proj_out) {
    __shared__ __align__(16) float Xs[16][68];
    __shared__ __align__(16) float Ws[16][68];
    if (blockIdx.x < 64) {
        fc_body(gate_in, Wg1, bg1, g1h, 960, 1024, 16, blockIdx.x, 1, Xs, Ws);
    } else {
        proj_body(P, pools, proj_out, blockIdx.x - 64, Xs, Ws);
    }
}

// ---------------------------------------------------------------------------
// Gate fc3 (K=512 -> 5 logits) + top-2 + softmax. One block per batch.
// jax.lax.top_k tie rule: lower index wins on equality (strict >).
// ---------------------------------------------------------------------------
__global__ __launch_bounds__(256) void fc3_top2_kernel(const float* __restrict__ X,
        const float* __restrict__ W, const float* __restrict__ bias,
        int* __restrict__ topi, float* __restrict__ wsm,
        float* __restrict__ out_gl, float* __restrict__ out_topi,
        float* __restrict__ out_w) {
    const int b    = blockIdx.x;
    const int tid  = threadIdx.x;
    const int lane = tid & 63;
    const int wv   = tid >> 6;
    __shared__ float red[4][5];
    const float* x = X + (size_t)b * 512;
    float acc[5] = {0.f, 0.f, 0.f, 0.f, 0.f};
    for (int k = tid; k < 512; k += 256) {
        float xv = x[k];
        const float* wr = W + (size_t)k * 5;
        acc[0] += xv * wr[0]; acc[1] += xv * wr[1]; acc[2] += xv * wr[2];
        acc[3] += xv * wr[3]; acc[4] += xv * wr[4];
    }
    #pragma unroll
    for (int off = 32; off > 0; off >>= 1) {
        #pragma unroll
        for (int j = 0; j < 5; ++j) acc[j] += __shfl_down(acc[j], off, 64);
    }
    if (lane == 0) {
        #pragma unroll
        for (int j = 0; j < 5; ++j) red[wv][j] = acc[j];
    }
    __syncthreads();
    if (tid == 0) {
        float v[5];
        #pragma unroll
        for (int j = 0; j < 5; ++j)
            v[j] = ((red[0][j] + red[1][j]) + (red[2][j] + red[3][j])) + bias[j];
        int i0 = 0;
        #pragma unroll
        for (int i = 1; i < 5; ++i) if (v[i] > v[i0]) i0 = i;
        int i1 = -1;
        #pragma unroll
        for (int i = 0; i < 5; ++i) {
            if (i == i0) continue;
            if (i1 < 0 || v[i] > v[i1]) i1 = i;
        }
        float e1 = __expf(v[i1] - v[i0]);
        float inv = 1.f / (1.f + e1);
        float w0 = inv, w1 = e1 * inv;
        topi[b * 2] = i0; topi[b * 2 + 1] = i1;
        wsm[b * 2] = w0;  wsm[b * 2 + 1] = w1;
        #pragma unroll
        for (int j = 0; j < 5; ++j) out_gl[b * 5 + j] = v[j];
        out_topi[b * 2]     = (float)i0;
        out_topi[b * 2 + 1] = (float)i1;
        out_w[b * 2]     = w0;
        out_w[b * 2 + 1] = w1;
    }
}

// ---------------------------------------------------------------------------
// mixln: gather the two selected projections per batch, LayerNorm + exact
// GELU + softmax-weighted sum. One block of 512 per batch (verified R6).
// ---------------------------------------------------------------------------
__global__ __launch_bounds__(512) void mixln_kernel(ProjParams P,
        const float* __restrict__ proj_out, const int* __restrict__ topi,
        const float* __restrict__ wsm, float* __restrict__ mix) {
    const int b = blockIdx.x;
    const int f = threadIdx.x;
    __shared__ float redS[8], redQ[8];
    __shared__ float s_mu, s_rstd;

    float acc = 0.f;
    for (int j = 0; j < 2; ++j) {
        __syncthreads();
        const int st = topi[b * 2 + j];
        float h = proj_out[(size_t)st * 131072 + (size_t)b * 512 + f];

        float s = h, q = h * h;
        #pragma unroll
        for (int off = 32; off > 0; off >>= 1) {
            s += __shfl_down(s, off, 64);
            q += __shfl_down(q, off, 64);
        }
        const int lane = threadIdx.x & 63, wid = threadIdx.x >> 6;
        if (lane == 0) { redS[wid] = s; redQ[wid] = q; }
        __syncthreads();
        if (threadIdx.x == 0) {
            float ts = 0.f, tq = 0.f;
            #pragma unroll
            for (int i = 0; i < 8; ++i) { ts += redS[i]; tq += redQ[i]; }
            float mu  = ts * (1.f / 512.f);
            float var = tq * (1.f / 512.f) - mu * mu;
            s_mu   = mu;
            s_rstd = rsqrtf(var + 1e-5f);
        }
        __syncthreads();

        float x  = (h - s_mu) * s_rstd * P.g[st][f] + P.be[st][f];
        float ge = 0.5f * x * (1.f + erff(x * 0.70710678118654752f));
        acc += wsm[b * 2 + j] * ge;
    }
    mix[(size_t)b * 512 + f] = acc;
}

// ---------------------------------------------------------------------------
extern "C" void kernel_launch(void* const* d_in, const int* in_sizes, int n_in,
                              void* d_out, int out_size, void* d_ws, size_t ws_size,
                              hipStream_t stream) {
    const int B = 256;

    const float* s1 = (const float*)d_in[0];
    const float* s2 = (const float*)d_in[1];
    const float* s3 = (const float*)d_in[2];
    const float* s4 = (const float*)d_in[3];
    const float* s5 = (const float*)d_in[4];
    const float* ff = (const float*)d_in[5];
    const float *Wp[5], *bp[5], *g[5], *be[5];
    for (int i = 0; i < 5; ++i) {
        Wp[i] = (const float*)d_in[6 + 4 * i];
        bp[i] = (const float*)d_in[7 + 4 * i];
        g[i]  = (const float*)d_in[8 + 4 * i];
        be[i] = (const float*)d_in[9 + 4 * i];
    }
    const float* Wg1 = (const float*)d_in[26]; const float* bg1 = (const float*)d_in[27];
    const float* Wg2 = (const float*)d_in[28]; const float* bg2 = (const float*)d_in[29];
    const float* Wg3 = (const float*)d_in[30]; const float* bg3 = (const float*)d_in[31];
    const float* Wc1 = (const float*)d_in[32]; const float* bc1 = (const float*)d_in[33];
    const float* Wc2 = (const float*)d_in[34]; const float* bc2 = (const float*)d_in[35];
    const float* Wc3 = (const float*)d_in[36]; const float* bc3 = (const float*)d_in[37];

    // ---- workspace layout (fp32 elements) ----
    float* ws = (float*)d_ws;
    const int Ks[5]   = {16, 24, 40, 80, 160};
    const int poff[5] = {0, 4096, 10240, 20480, 40960};
    float* pools    = ws;                                     // 81920
    float* gate_in  = ws + 81920;                             // 245760
    float* g1h      = ws + 327680;                            // 262144
    float* g2h      = ws + 589824;                            // 131072
    float* wsm      = ws + 720896;                            // 512
    int*   topi     = (int*)(ws + 721408);                    // 512
    float* mix      = ws + 721920;                            // 131072
    float* proj_out = ws + 852992;                            // 655360
    float* c1h      = ws + 1508352;                           // 262144
    float* c2h      = ws + 1770496;                           // 131072

    float* out      = (float*)d_out;
    float* out_gl   = out + 256000;
    float* out_topi = out + 257280;
    float* out_w    = out + 257792;

    // ---- 1) ALL pooling in one dispatch ----
    {
        PoolAll S;
        const float* srcs[4] = { s1, s2, s3, s4 };
        const int rls[4]  = { 112 * 112, 56 * 56, 28 * 28, 14 * 14 };
        const int rows[4] = { B * 16, B * 24, B * 40, B * 80 };
        int cum = 0;
        for (int i = 0; i < 4; ++i) {
            S.src[i] = srcs[i]; S.dst[i] = pools + poff[i]; S.n4[i] = rls[i] / 4;
            cum += rows[i]; S.cum[i] = cum; S.inv[i] = 1.f / rls[i];
        }
        S.nbb   = (cum * 64) / 256;           // 10240
        S.s5    = s5; S.ff = ff;
        S.dst5  = pools + poff[4]; S.dstf = gate_in;
        S.rows5 = B * 160;
        int small_blocks = (S.rows5 + B * 960) / 64;   // 4480
        pool_all_kernel<<<S.nbb + small_blocks, 256, 0, stream>>>(S);
    }

    ProjParams P;
    for (int i = 0; i < 5; ++i) {
        P.W[i] = Wp[i]; P.bp[i] = bp[i]; P.g[i] = g[i]; P.be[i] = be[i];
        P.K[i] = Ks[i]; P.poff[i] = poff[i];
    }

    // ---- 2) gate1 (KS=1) + all 5 projections, one dispatch ----
    gate1_proj_kernel<<<64 + 160, 256, 0, stream>>>(gate_in, Wg1, bg1, g1h,
                                                    P, pools, proj_out);
    // ---- 3) gate2 (KS=1) ----
    fc_plain_kernel<<<4 * 8, 256, 0, stream>>>(g1h, Wg2, bg2, g2h, 1024, 512, 8, 1);
    // ---- 4) fc3 + top2 ----
    fc3_top2_kernel<<<B, 256, 0, stream>>>(g2h, Wg3, bg3, topi, wsm,
                                           out_gl, out_topi, out_w);
    // ---- 5) mixln ----
    mixln_kernel<<<B, 512, 0, stream>>>(P, proj_out, topi, wsm, mix);
    // ---- 6..8) classifier MLP, one dispatch per layer (KS=1) ----
    fc_plain_kernel<<<4 * 16, 256, 0, stream>>>(mix, Wc1, bc1, c1h, 512, 1024, 16, 1);
    fc_plain_kernel<<<4 * 8, 256, 0, stream>>>(c1h, Wc2, bc2, c2h, 1024, 512, 8, 1);
    fc_plain_kernel<<<4 * 16, 256, 0, stream>>>(c2h, Wc3, bc3, out, 512, 1000, 16, 0);
}

// Round 11
// 677.532 us; speedup vs baseline: 1.3534x; 1.0548x over previous
//
#include <hip/hip_runtime.h>
#include <math.h>

// All tensors fp32. B=256, F=512, H=1024, C=1000.

// ---------------------------------------------------------------------------
// pool_all: ONE dispatch for all pooling (verified R7/R9/R10, ~135 us wall).
// ---------------------------------------------------------------------------
struct PoolAll {
    const float* src[4];
    float*       dst[4];
    int n4[4];
    int cum[4];
    float inv[4];
    const float* s5;
    const float* ff;
    float*       dst5;
    float*       dstf;
    int nbb;
    int rows5;
};

__global__ __launch_bounds__(256) void pool_all_kernel(PoolAll S) {
    __shared__ float lds[64 * 49];
    if ((int)blockIdx.x < S.nbb) {
        int gid  = blockIdx.x * 256 + threadIdx.x;
        int wave = gid >> 6;
        int lane = gid & 63;
        if (wave >= S.cum[3]) return;
        int s = 0;
        #pragma unroll
        for (int i = 0; i < 3; ++i) if (wave >= S.cum[i]) s = i + 1;
        int row = wave - (s == 0 ? 0 : S.cum[s - 1]);
        const int n4 = S.n4[s];
        const float4* p4 = (const float4*)(S.src[s]) + (size_t)row * n4;
        float a0 = 0.f, a1 = 0.f, a2 = 0.f, a3 = 0.f;
        float a4 = 0.f, a5 = 0.f, a6 = 0.f, a7 = 0.f;
        int k = lane;
        for (; k + 448 < n4; k += 512) {
            float4 v0 = p4[k];       float4 v1 = p4[k + 64];
            float4 v2 = p4[k + 128]; float4 v3 = p4[k + 192];
            float4 v4 = p4[k + 256]; float4 v5 = p4[k + 320];
            float4 v6 = p4[k + 384]; float4 v7 = p4[k + 448];
            a0 += (v0.x + v0.y) + (v0.z + v0.w);
            a1 += (v1.x + v1.y) + (v1.z + v1.w);
            a2 += (v2.x + v2.y) + (v2.z + v2.w);
            a3 += (v3.x + v3.y) + (v3.z + v3.w);
            a4 += (v4.x + v4.y) + (v4.z + v4.w);
            a5 += (v5.x + v5.y) + (v5.z + v5.w);
            a6 += (v6.x + v6.y) + (v6.z + v6.w);
            a7 += (v7.x + v7.y) + (v7.z + v7.w);
        }
        for (; k + 192 < n4; k += 256) {
            float4 v0 = p4[k];       float4 v1 = p4[k + 64];
            float4 v2 = p4[k + 128]; float4 v3 = p4[k + 192];
            a0 += (v0.x + v0.y) + (v0.z + v0.w);
            a1 += (v1.x + v1.y) + (v1.z + v1.w);
            a2 += (v2.x + v2.y) + (v2.z + v2.w);
            a3 += (v3.x + v3.y) + (v3.z + v3.w);
        }
        for (; k < n4; k += 64) {
            float4 v = p4[k];
            a0 += (v.x + v.y) + (v.z + v.w);
        }
        float acc = ((a0 + a1) + (a2 + a3)) + ((a4 + a5) + (a6 + a7));
        #pragma unroll
        for (int off = 32; off > 0; off >>= 1) acc += __shfl_down(acc, off, 64);
        if (lane == 0) S.dst[s][row] = acc * S.inv[s];
        return;
    }
    const int tid  = threadIdx.x;
    const int row0 = (blockIdx.x - S.nbb) * 64;
    const float* src;
    float* dst;
    int rbase;
    if (row0 < S.rows5) { src = S.s5; dst = S.dst5; rbase = row0; }
    else                { src = S.ff; dst = S.dstf; rbase = row0 - S.rows5; }
    const float4* p4 = (const float4*)(src + (size_t)rbase * 49);
    float4* l4 = (float4*)lds;
    float4 v0 = p4[tid];
    float4 v1 = p4[tid + 256];
    float4 v2 = p4[tid + 512];
    float4 v3;
    const bool t3 = (tid < 784 - 768);
    if (t3) v3 = p4[tid + 768];
    l4[tid]       = v0;
    l4[tid + 256] = v1;
    l4[tid + 512] = v2;
    if (t3) l4[tid + 768] = v3;
    __syncthreads();
    const int r  = tid >> 2;
    const int c0 = tid & 3;
    float s = 0.f;
    #pragma unroll
    for (int c = c0; c < 49; c += 4) s += lds[r * 49 + c];
    s += __shfl_down(s, 2, 64);
    s += __shfl_down(s, 1, 64);
    if (c0 == 0) dst[rbase + r] = s * (1.f / 49.f);
}

// ---------------------------------------------------------------------------
// fc_wave: KS=1 GEMM, 64x64 tile, 512 threads = 8 waves. K split across the
// 8 waves (contiguous eighths); each wave stages its OWN LDS pane (wave-
// synchronous global->reg->ds_write->ds_read, in-wave lgkmcnt ordering) ->
// ZERO barriers in the K-loop (the R10-measured barrier-chain killer).
// Register prefetch hides global latency under the per-step FMA block.
// Epilogue: sequential wave-ordered LDS accumulation (deterministic), wave 7
// adds bias (+ReLU) and stores. K % 8 == 0; M = 256; N masked.
// smem: >= 8704 floats (Xw 8x[8][68] | Ww 8x[8][68]; overlaid Cred[64][72]).
// ---------------------------------------------------------------------------
__device__ __forceinline__ void ldw2(const float* __restrict__ W, int row,
        int nc, int N, float4& a, float4& b) {
    const float* p = W + (size_t)row * N + nc;
    if (nc + 7 < N) {
        a = *(const float4*)p;
        b = *(const float4*)(p + 4);
    } else {
        float t[8];
        #pragma unroll
        for (int j = 0; j < 8; ++j) t[j] = (nc + j < N) ? p[j] : 0.f;
        a = make_float4(t[0], t[1], t[2], t[3]);
        b = make_float4(t[4], t[5], t[6], t[7]);
    }
}

__device__ void fc_wave_body(const float* __restrict__ X,
        const float* __restrict__ W, const float* __restrict__ bias,
        float* __restrict__ Y, int K, int N, int ntiles, int tile, int do_relu,
        float* smem) {
    const int tid  = threadIdx.x;          // 0..511
    const int w    = tid >> 6;             // wave 0..7
    const int lane = tid & 63;
    const int mt = tile / ntiles, nt = tile - mt * ntiles;
    const int m0 = mt * 64, n0 = nt * 64;
    const int Kq = K >> 3;                 // K/8, multiple of 8
    const int k0 = w * Kq;

    float* Xw = smem + w * 544;            // [8][68] wave-private
    float* Ww = smem + 4352 + w * 544;     // [8][68] wave-private

    const int lm = lane >> 3;              // micro row group (8 rows)
    const int ln = lane & 7;               // micro col group (8 cols)

    // staging assignment
    const float* xp = X + (size_t)(m0 + lane) * K + k0;   // row=lane, 8 k's
    const int wr = lane >> 3;              // k-row 0..7
    const int nc = n0 + (lane & 7) * 8;    // col octet

    float4 acc[8][2];
    #pragma unroll
    for (int i = 0; i < 8; ++i) {
        acc[i][0] = make_float4(0.f, 0.f, 0.f, 0.f);
        acc[i][1] = make_float4(0.f, 0.f, 0.f, 0.f);
    }

    float4 xa = *(const float4*)(xp);
    float4 xb = *(const float4*)(xp + 4);
    float4 wa, wb;
    ldw2(W, k0 + wr, nc, N, wa, wb);

    for (int kt = 0; kt < Kq; kt += 8) {
        // wave-private staging (no barrier; in-wave lgkmcnt orders wr->rd)
        Xw[0 * 68 + lane] = xa.x;
        Xw[1 * 68 + lane] = xa.y;
        Xw[2 * 68 + lane] = xa.z;
        Xw[3 * 68 + lane] = xa.w;
        Xw[4 * 68 + lane] = xb.x;
        Xw[5 * 68 + lane] = xb.y;
        Xw[6 * 68 + lane] = xb.z;
        Xw[7 * 68 + lane] = xb.w;
        *(float4*)&Ww[wr * 68 + (nc - n0)]     = wa;
        *(float4*)&Ww[wr * 68 + (nc - n0) + 4] = wb;
        if (kt + 8 < Kq) {                 // prefetch next step
            xa = *(const float4*)(xp + kt + 8);
            xb = *(const float4*)(xp + kt + 12);
            ldw2(W, k0 + kt + 8 + wr, nc, N, wa, wb);
        }
        #pragma unroll
        for (int kk = 0; kk < 8; ++kk) {
            float4 xv0 = *(const float4*)&Xw[kk * 68 + lm * 8];
            float4 xv1 = *(const float4*)&Xw[kk * 68 + lm * 8 + 4];
            float4 wv0 = *(const float4*)&Ww[kk * 68 + ln * 8];
            float4 wv1 = *(const float4*)&Ww[kk * 68 + ln * 8 + 4];
            float xs[8] = { xv0.x, xv0.y, xv0.z, xv0.w,
                            xv1.x, xv1.y, xv1.z, xv1.w };
            #pragma unroll
            for (int i = 0; i < 8; ++i) {
                acc[i][0].x += xs[i] * wv0.x; acc[i][0].y += xs[i] * wv0.y;
                acc[i][0].z += xs[i] * wv0.z; acc[i][0].w += xs[i] * wv0.w;
                acc[i][1].x += xs[i] * wv1.x; acc[i][1].y += xs[i] * wv1.y;
                acc[i][1].z += xs[i] * wv1.z; acc[i][1].w += xs[i] * wv1.w;
            }
        }
    }

    // deterministic cross-wave reduce via overlaid LDS (stride 72 vs banks)
    __syncthreads();                       // all staging use of smem done
    float* Cred = smem;                    // [64][72] = 4608 floats
    for (int wv = 0; wv < 7; ++wv) {
        if (w == wv) {
            #pragma unroll
            for (int i = 0; i < 8; ++i) {
                float* cp = &Cred[(lm * 8 + i) * 72 + ln * 8];
                if (wv == 0) {
                    *(float4*)cp       = acc[i][0];
                    *(float4*)(cp + 4) = acc[i][1];
                } else {
                    float4 c0 = *(const float4*)cp;
                    float4 c1 = *(const float4*)(cp + 4);
                    c0.x += acc[i][0].x; c0.y += acc[i][0].y;
                    c0.z += acc[i][0].z; c0.w += acc[i][0].w;
                    c1.x += acc[i][1].x; c1.y += acc[i][1].y;
                    c1.z += acc[i][1].z; c1.w += acc[i][1].w;
                    *(float4*)cp       = c0;
                    *(float4*)(cp + 4) = c1;
                }
            }
        }
        __syncthreads();
    }
    if (w == 7) {
        const int nb = n0 + ln * 8;
        float bb[8];
        #pragma unroll
        for (int j = 0; j < 8; ++j) bb[j] = (nb + j < N) ? bias[nb + j] : 0.f;
        #pragma unroll
        for (int i = 0; i < 8; ++i) {
            const int row = m0 + lm * 8 + i;
            float* cp = &Cred[(lm * 8 + i) * 72 + ln * 8];
            float v[8];
            #pragma unroll
            for (int j = 0; j < 4; ++j) {
                v[j]     = cp[j]     ;
                v[j + 4] = cp[j + 4] ;
            }
            v[0] += acc[i][0].x; v[1] += acc[i][0].y;
            v[2] += acc[i][0].z; v[3] += acc[i][0].w;
            v[4] += acc[i][1].x; v[5] += acc[i][1].y;
            v[6] += acc[i][1].z; v[7] += acc[i][1].w;
            float* yp = Y + (size_t)row * N + nb;
            #pragma unroll
            for (int j = 0; j < 8; ++j) {
                if (nb + j < N) {
                    float o = v[j] + bb[j];
                    if (do_relu) o = fmaxf(o, 0.f);
                    yp[j] = o;
                }
            }
        }
    }
}

__global__ __launch_bounds__(512) void fc_wave_kernel(const float* __restrict__ X,
        const float* __restrict__ W, const float* __restrict__ bias,
        float* __restrict__ Y, int K, int N, int ntiles, int do_relu) {
    __shared__ __align__(16) float smem[8704];
    fc_wave_body(X, W, bias, Y, K, N, ntiles, blockIdx.x, do_relu, smem);
}

// ---------------------------------------------------------------------------
// proj_body: projection GEMM task (TK=8, verified R6/R9/R10), parameterized
// on a 256-thread id and private LDS pointers (flat [8][68] x2).
// ---------------------------------------------------------------------------
struct ProjParams {
    const float* W[5];
    const float* bp[5];
    const float* g[5];
    const float* be[5];
    int K[5];
    int poff[5];
};

__device__ void proj_body(const ProjParams& P, const float* __restrict__ pools,
        float* __restrict__ proj_out, int task, int t,
        float* Xs, float* Ws) {
    const int st  = task >> 5;
    const int bid = task & 31;
    const int K  = P.K[st];
    const float* X = pools + P.poff[st];
    const float* W = P.W[st];
    const int N = 512;
    int mt  = bid >> 3;
    int nt  = bid & 7;
    const int m0 = mt * 64, n0 = nt * 64;

    const int tm = t & 15;
    const int tn = t >> 4;
    const int xa = t >> 3, xb = t & 7;
    const int wc = t & 63, wb = t >> 6;
    const int nw = n0 + wc;

    float4 acc[4];
    #pragma unroll
    for (int r = 0; r < 4; ++r) acc[r] = make_float4(0.f, 0.f, 0.f, 0.f);

    float x0, x1, w0v, w1v;
    x0  = X[(size_t)(m0 + xa) * K + xb];
    x1  = X[(size_t)(m0 + xa + 32) * K + xb];
    w0v = W[(size_t)wb * N + nw];
    w1v = W[(size_t)(wb + 4) * N + nw];

    for (int kt = 0; kt < K; kt += 8) {
        __syncthreads();
        Xs[xb * 68 + xa] = x0; Xs[xb * 68 + xa + 32] = x1;
        Ws[wb * 68 + wc] = w0v; Ws[(wb + 4) * 68 + wc] = w1v;
        __syncthreads();
        if (kt + 8 < K) {
            x0  = X[(size_t)(m0 + xa) * K + kt + 8 + xb];
            x1  = X[(size_t)(m0 + xa + 32) * K + kt + 8 + xb];
            w0v = W[(size_t)(kt + 8 + wb) * N + nw];
            w1v = W[(size_t)(kt + 8 + wb + 4) * N + nw];
        }
        #pragma unroll
        for (int kk = 0; kk < 8; ++kk) {
            float4 xr = *(const float4*)&Xs[kk * 68 + tm * 4];
            float4 wr = *(const float4*)&Ws[kk * 68 + tn * 4];
            acc[0].x += xr.x * wr.x; acc[0].y += xr.x * wr.y;
            acc[0].z += xr.x * wr.z; acc[0].w += xr.x * wr.w;
            acc[1].x += xr.y * wr.x; acc[1].y += xr.y * wr.y;
            acc[1].z += xr.y * wr.z; acc[1].w += xr.y * wr.w;
            acc[2].x += xr.z * wr.x; acc[2].y += xr.z * wr.y;
            acc[2].z += xr.z * wr.z; acc[2].w += xr.z * wr.w;
            acc[3].x += xr.w * wr.x; acc[3].y += xr.w * wr.y;
            acc[3].z += xr.w * wr.z; acc[3].w += xr.w * wr.w;
        }
    }
    const int nbase = n0 + tn * 4;
    float4 bb = *(const float4*)(P.bp[st] + nbase);
    float* op = proj_out + (size_t)st * 131072 + (size_t)(m0 + tm * 4) * N + nbase;
    #pragma unroll
    for (int r = 0; r < 4; ++r) {
        float4 v = acc[r];
        v.x += bb.x; v.y += bb.y; v.z += bb.z; v.w += bb.w;
        *(float4*)(op + (size_t)r * N) = v;
    }
}

// gate1 (64 fc_wave tiles) + proj (80 blocks x 2 same-stage tasks) merged.
__global__ __launch_bounds__(512) void gate1_proj_kernel(
        const float* __restrict__ gate_in, const float* __restrict__ Wg1,
        const float* __restrict__ bg1, float* __restrict__ g1h,
        ProjParams P, const float* __restrict__ pools,
        float* __restrict__ proj_out) {
    __shared__ __align__(16) float smem[8704];
    if (blockIdx.x < 64) {
        fc_wave_body(gate_in, Wg1, bg1, g1h, 960, 1024, 16, blockIdx.x, 1, smem);
    } else {
        // two tasks per block, guaranteed same stage (task=2q, 2q+1)
        const int half = threadIdx.x >> 8;       // 0 or 1
        const int t    = threadIdx.x & 255;
        const int task = (blockIdx.x - 64) * 2 + half;
        float* base = smem + half * 1088;        // 2x(544+544)
        proj_body(P, pools, proj_out, task, t, base, base + 544);
    }
}

// ---------------------------------------------------------------------------
// Gate fc3 (K=512 -> 5 logits) + top-2 + softmax. One block per batch.
// jax.lax.top_k tie rule: lower index wins on equality (strict >).
// ---------------------------------------------------------------------------
__global__ __launch_bounds__(256) void fc3_top2_kernel(const float* __restrict__ X,
        const float* __restrict__ W, const float* __restrict__ bias,
        int* __restrict__ topi, float* __restrict__ wsm,
        float* __restrict__ out_gl, float* __restrict__ out_topi,
        float* __restrict__ out_w) {
    const int b    = blockIdx.x;
    const int tid  = threadIdx.x;
    const int lane = tid & 63;
    const int wv   = tid >> 6;
    __shared__ float red[4][5];
    const float* x = X + (size_t)b * 512;
    float acc[5] = {0.f, 0.f, 0.f, 0.f, 0.f};
    for (int k = tid; k < 512; k += 256) {
        float xv = x[k];
        const float* wr = W + (size_t)k * 5;
        acc[0] += xv * wr[0]; acc[1] += xv * wr[1]; acc[2] += xv * wr[2];
        acc[3] += xv * wr[3]; acc[4] += xv * wr[4];
    }
    #pragma unroll
    for (int off = 32; off > 0; off >>= 1) {
        #pragma unroll
        for (int j = 0; j < 5; ++j) acc[j] += __shfl_down(acc[j], off, 64);
    }
    if (lane == 0) {
        #pragma unroll
        for (int j = 0; j < 5; ++j) red[wv][j] = acc[j];
    }
    __syncthreads();
    if (tid == 0) {
        float v[5];
        #pragma unroll
        for (int j = 0; j < 5; ++j)
            v[j] = ((red[0][j] + red[1][j]) + (red[2][j] + red[3][j])) + bias[j];
        int i0 = 0;
        #pragma unroll
        for (int i = 1; i < 5; ++i) if (v[i] > v[i0]) i0 = i;
        int i1 = -1;
        #pragma unroll
        for (int i = 0; i < 5; ++i) {
            if (i == i0) continue;
            if (i1 < 0 || v[i] > v[i1]) i1 = i;
        }
        float e1 = __expf(v[i1] - v[i0]);
        float inv = 1.f / (1.f + e1);
        float w0 = inv, w1 = e1 * inv;
        topi[b * 2] = i0; topi[b * 2 + 1] = i1;
        wsm[b * 2] = w0;  wsm[b * 2 + 1] = w1;
        #pragma unroll
        for (int j = 0; j < 5; ++j) out_gl[b * 5 + j] = v[j];
        out_topi[b * 2]     = (float)i0;
        out_topi[b * 2 + 1] = (float)i1;
        out_w[b * 2]     = w0;
        out_w[b * 2 + 1] = w1;
    }
}

// ---------------------------------------------------------------------------
// mixln: gather the two selected projections per batch, LayerNorm + exact
// GELU + softmax-weighted sum. One block of 512 per batch (verified R6).
// ---------------------------------------------------------------------------
__global__ __launch_bounds__(512) void mixln_kernel(ProjParams P,
        const float* __restrict__ proj_out, const int* __restrict__ topi,
        const float* __restrict__ wsm, float* __restrict__ mix) {
    const int b = blockIdx.x;
    const int f = threadIdx.x;
    __shared__ float redS[8], redQ[8];
    __shared__ float s_mu, s_rstd;

    float acc = 0.f;
    for (int j = 0; j < 2; ++j) {
        __syncthreads();
        const int st = topi[b * 2 + j];
        float h = proj_out[(size_t)st * 131072 + (size_t)b * 512 + f];

        float s = h, q = h * h;
        #pragma unroll
        for (int off = 32; off > 0; off >>= 1) {
            s += __shfl_down(s, off, 64);
            q += __shfl_down(q, off, 64);
        }
        const int lane = threadIdx.x & 63, wid = threadIdx.x >> 6;
        if (lane == 0) { redS[wid] = s; redQ[wid] = q; }
        __syncthreads();
        if (threadIdx.x == 0) {
            float ts = 0.f, tq = 0.f;
            #pragma unroll
            for (int i = 0; i < 8; ++i) { ts += redS[i]; tq += redQ[i]; }
            float mu  = ts * (1.f / 512.f);
            float var = tq * (1.f / 512.f) - mu * mu;
            s_mu   = mu;
            s_rstd = rsqrtf(var + 1e-5f);
        }
        __syncthreads();

        float x  = (h - s_mu) * s_rstd * P.g[st][f] + P.be[st][f];
        float ge = 0.5f * x * (1.f + erff(x * 0.70710678118654752f));
        acc += wsm[b * 2 + j] * ge;
    }
    mix[(size_t)b * 512 + f] = acc;
}

// ---------------------------------------------------------------------------
extern "C" void kernel_launch(void* const* d_in, const int* in_sizes, int n_in,
                              void* d_out, int out_size, void* d_ws, size_t ws_size,
                              hipStream_t stream) {
    const int B = 256;

    const float* s1 = (const float*)d_in[0];
    const float* s2 = (const float*)d_in[1];
    const float* s3 = (const float*)d_in[2];
    const float* s4 = (const float*)d_in[3];
    const float* s5 = (const float*)d_in[4];
    const float* ff = (const float*)d_in[5];
    const float *Wp[5], *bp[5], *g[5], *be[5];
    for (int i = 0; i < 5; ++i) {
        Wp[i] = (const float*)d_in[6 + 4 * i];
        bp[i] = (const float*)d_in[7 + 4 * i];
        g[i]  = (const float*)d_in[8 + 4 * i];
        be[i] = (const float*)d_in[9 + 4 * i];
    }
    const float* Wg1 = (const float*)d_in[26]; const float* bg1 = (const float*)d_in[27];
    const float* Wg2 = (const float*)d_in[28]; const float* bg2 = (const float*)d_in[29];
    const float* Wg3 = (const float*)d_in[30]; const float* bg3 = (const float*)d_in[31];
    const float* Wc1 = (const float*)d_in[32]; const float* bc1 = (const float*)d_in[33];
    const float* Wc2 = (const float*)d_in[34]; const float* bc2 = (const float*)d_in[35];
    const float* Wc3 = (const float*)d_in[36]; const float* bc3 = (const float*)d_in[37];

    // ---- workspace layout (fp32 elements) ----
    float* ws = (float*)d_ws;
    const int Ks[5]   = {16, 24, 40, 80, 160};
    const int poff[5] = {0, 4096, 10240, 20480, 40960};
    float* pools    = ws;                                     // 81920
    float* gate_in  = ws + 81920;                             // 245760
    float* g1h      = ws + 327680;                            // 262144
    float* g2h      = ws + 589824;                            // 131072
    float* wsm      = ws + 720896;                            // 512
    int*   topi     = (int*)(ws + 721408);                    // 512
    float* mix      = ws + 721920;                            // 131072
    float* proj_out = ws + 852992;                            // 655360
    float* c1h      = ws + 1508352;                           // 262144
    float* c2h      = ws + 1770496;                           // 131072

    float* out      = (float*)d_out;
    float* out_gl   = out + 256000;
    float* out_topi = out + 257280;
    float* out_w    = out + 257792;

    // ---- 1) ALL pooling in one dispatch ----
    {
        PoolAll S;
        const float* srcs[4] = { s1, s2, s3, s4 };
        const int rls[4]  = { 112 * 112, 56 * 56, 28 * 28, 14 * 14 };
        const int rows[4] = { B * 16, B * 24, B * 40, B * 80 };
        int cum = 0;
        for (int i = 0; i < 4; ++i) {
            S.src[i] = srcs[i]; S.dst[i] = pools + poff[i]; S.n4[i] = rls[i] / 4;
            cum += rows[i]; S.cum[i] = cum; S.inv[i] = 1.f / rls[i];
        }
        S.nbb   = (cum * 64) / 256;           // 10240
        S.s5    = s5; S.ff = ff;
        S.dst5  = pools + poff[4]; S.dstf = gate_in;
        S.rows5 = B * 160;
        int small_blocks = (S.rows5 + B * 960) / 64;   // 4480
        pool_all_kernel<<<S.nbb + small_blocks, 256, 0, stream>>>(S);
    }

    ProjParams P;
    for (int i = 0; i < 5; ++i) {
        P.W[i] = Wp[i]; P.bp[i] = bp[i]; P.g[i] = g[i]; P.be[i] = be[i];
        P.K[i] = Ks[i]; P.poff[i] = poff[i];
    }

    // ---- 2) gate1 (fc_wave) + all 5 projections, one dispatch ----
    gate1_proj_kernel<<<64 + 80, 512, 0, stream>>>(gate_in, Wg1, bg1, g1h,
                                                   P, pools, proj_out);
    // ---- 3) gate2 (fc_wave) ----
    fc_wave_kernel<<<4 * 8, 512, 0, stream>>>(g1h, Wg2, bg2, g2h, 1024, 512, 8, 1);
    // ---- 4) fc3 + top2 ----
    fc3_top2_kernel<<<B, 256, 0, stream>>>(g2h, Wg3, bg3, topi, wsm,
                                           out_gl, out_topi, out_w);
    // ---- 5) mixln ----
    mixln_kernel<<<B, 512, 0, stream>>>(P, proj_out, topi, wsm, mix);
    // ---- 6..8) classifier MLP (fc_wave) ----
    fc_wave_kernel<<<4 * 16, 512, 0, stream>>>(mix, Wc1, bc1, c1h, 512, 1024, 16, 1);
    fc_wave_kernel<<<4 * 8, 512, 0, stream>>>(c1h, Wc2, bc2, c2h, 1024, 512, 8, 1);
    fc_wave_kernel<<<4 * 16, 512, 0, stream>>>(c2h, Wc3, bc3, out, 512, 1000, 16, 0);
}

// Round 13
// 532.952 us; speedup vs baseline: 1.7205x; 1.2713x over previous
//
#include <hip/hip_runtime.h>
#include <math.h>

// All tensors fp32. B=256, F=512, H=1024, C=1000.

typedef float nt4 __attribute__((ext_vector_type(4)));

__device__ __forceinline__ float4 ntload(const float4* p) {
    nt4 v = __builtin_nontemporal_load((const nt4*)p);
    return make_float4(v.x, v.y, v.z, v.w);
}

// ---------------------------------------------------------------------------
// pool_all: ONE dispatch for all pooling (structure verified R7/R9/R10/R11).
// NT loads: each input byte is read exactly once; NT bypasses the L2/L3 path
// (measured ~2.8 TB/s wall) and streams from HBM (~6.3 TB/s).
// ---------------------------------------------------------------------------
struct PoolAll {
    const float* src[4];
    float*       dst[4];
    int n4[4];
    int cum[4];
    float inv[4];
    const float* s5;
    const float* ff;
    float*       dst5;
    float*       dstf;
    int nbb;
    int rows5;
};

__global__ __launch_bounds__(256) void pool_all_kernel(PoolAll S) {
    __shared__ float lds[64 * 49];
    if ((int)blockIdx.x < S.nbb) {
        int gid  = blockIdx.x * 256 + threadIdx.x;
        int wave = gid >> 6;
        int lane = gid & 63;
        if (wave >= S.cum[3]) return;
        int s = 0;
        #pragma unroll
        for (int i = 0; i < 3; ++i) if (wave >= S.cum[i]) s = i + 1;
        int row = wave - (s == 0 ? 0 : S.cum[s - 1]);
        const int n4 = S.n4[s];
        const float4* p4 = (const float4*)(S.src[s]) + (size_t)row * n4;
        float a0 = 0.f, a1 = 0.f, a2 = 0.f, a3 = 0.f;
        float a4 = 0.f, a5 = 0.f, a6 = 0.f, a7 = 0.f;
        int k = lane;
        for (; k + 448 < n4; k += 512) {
            float4 v0 = ntload(p4 + k);       float4 v1 = ntload(p4 + k + 64);
            float4 v2 = ntload(p4 + k + 128); float4 v3 = ntload(p4 + k + 192);
            float4 v4 = ntload(p4 + k + 256); float4 v5 = ntload(p4 + k + 320);
            float4 v6 = ntload(p4 + k + 384); float4 v7 = ntload(p4 + k + 448);
            a0 += (v0.x + v0.y) + (v0.z + v0.w);
            a1 += (v1.x + v1.y) + (v1.z + v1.w);
            a2 += (v2.x + v2.y) + (v2.z + v2.w);
            a3 += (v3.x + v3.y) + (v3.z + v3.w);
            a4 += (v4.x + v4.y) + (v4.z + v4.w);
            a5 += (v5.x + v5.y) + (v5.z + v5.w);
            a6 += (v6.x + v6.y) + (v6.z + v6.w);
            a7 += (v7.x + v7.y) + (v7.z + v7.w);
        }
        for (; k + 192 < n4; k += 256) {
            float4 v0 = ntload(p4 + k);       float4 v1 = ntload(p4 + k + 64);
            float4 v2 = ntload(p4 + k + 128); float4 v3 = ntload(p4 + k + 192);
            a0 += (v0.x + v0.y) + (v0.z + v0.w);
            a1 += (v1.x + v1.y) + (v1.z + v1.w);
            a2 += (v2.x + v2.y) + (v2.z + v2.w);
            a3 += (v3.x + v3.y) + (v3.z + v3.w);
        }
        for (; k < n4; k += 64) {
            float4 v = ntload(p4 + k);
            a0 += (v.x + v.y) + (v.z + v.w);
        }
        float acc = ((a0 + a1) + (a2 + a3)) + ((a4 + a5) + (a6 + a7));
        #pragma unroll
        for (int off = 32; off > 0; off >>= 1) acc += __shfl_down(acc, off, 64);
        if (lane == 0) S.dst[s][row] = acc * S.inv[s];
        return;
    }
    const int tid  = threadIdx.x;
    const int row0 = (blockIdx.x - S.nbb) * 64;
    const float* src;
    float* dst;
    int rbase;
    if (row0 < S.rows5) { src = S.s5; dst = S.dst5; rbase = row0; }
    else                { src = S.ff; dst = S.dstf; rbase = row0 - S.rows5; }
    const float4* p4 = (const float4*)(src + (size_t)rbase * 49);
    float4* l4 = (float4*)lds;
    float4 v0 = ntload(p4 + tid);
    float4 v1 = ntload(p4 + tid + 256);
    float4 v2 = ntload(p4 + tid + 512);
    float4 v3;
    const bool t3 = (tid < 784 - 768);
    if (t3) v3 = ntload(p4 + tid + 768);
    l4[tid]       = v0;
    l4[tid + 256] = v1;
    l4[tid + 512] = v2;
    if (t3) l4[tid + 768] = v3;
    __syncthreads();
    const int r  = tid >> 2;
    const int c0 = tid & 3;
    float s = 0.f;
    #pragma unroll
    for (int c = c0; c < 49; c += 4) s += lds[r * 49 + c];
    s += __shfl_down(s, 2, 64);
    s += __shfl_down(s, 1, 64);
    if (c0 == 0) dst[rbase + r] = s * (1.f / 49.f);
}

// ---------------------------------------------------------------------------
// fc_tile: R6-verified LDS-tiled split-K SGEMM (tile 64x64, TK=16, 4x4 micro,
// float4 staging, register prefetch). Writes partials Pt[ks][M][N].
// ---------------------------------------------------------------------------
__device__ void fc_tile_body(const float* __restrict__ X,
        const float* __restrict__ W, float* __restrict__ Pt,
        int M, int K, int N, int Kc, int ntiles, int bid,
        float (*Xs)[68], float (*Ws)[68]) {
    const int tpk = 4 * ntiles;            // mtiles=4
    int ks  = bid / tpk;
    int rem = bid - ks * tpk;
    int mt  = rem / ntiles;
    int nt  = rem - mt * ntiles;
    const int m0 = mt * 64, n0 = nt * 64;
    const int k0 = ks * Kc;
    int k1 = k0 + Kc; if (k1 > K) k1 = K;

    const int tid = threadIdx.x;
    const int tm = tid & 15;
    const int tn = tid >> 4;
    const int xr = tid >> 2, xc = tid & 3;
    const int wr = tid >> 4, wc = tid & 15;
    const int nwc = n0 + wc * 4;

    float4 acc[4];
    #pragma unroll
    for (int r = 0; r < 4; ++r) acc[r] = make_float4(0.f, 0.f, 0.f, 0.f);

    float4 xv, wv;
    xv = *(const float4*)(X + (size_t)(m0 + xr) * K + k0 + xc * 4);
    if (nwc + 3 < N) {
        wv = *(const float4*)(W + (size_t)(k0 + wr) * N + nwc);
    } else {
        wv.x = (nwc + 0 < N) ? W[(size_t)(k0 + wr) * N + nwc + 0] : 0.f;
        wv.y = (nwc + 1 < N) ? W[(size_t)(k0 + wr) * N + nwc + 1] : 0.f;
        wv.z = (nwc + 2 < N) ? W[(size_t)(k0 + wr) * N + nwc + 2] : 0.f;
        wv.w = (nwc + 3 < N) ? W[(size_t)(k0 + wr) * N + nwc + 3] : 0.f;
    }

    for (int kt = k0; kt < k1; kt += 16) {
        __syncthreads();
        Xs[xc * 4 + 0][xr] = xv.x;
        Xs[xc * 4 + 1][xr] = xv.y;
        Xs[xc * 4 + 2][xr] = xv.z;
        Xs[xc * 4 + 3][xr] = xv.w;
        *(float4*)&Ws[wr][wc * 4] = wv;
        __syncthreads();
        if (kt + 16 < k1) {
            xv = *(const float4*)(X + (size_t)(m0 + xr) * K + kt + 16 + xc * 4);
            if (nwc + 3 < N) {
                wv = *(const float4*)(W + (size_t)(kt + 16 + wr) * N + nwc);
            } else {
                wv.x = (nwc + 0 < N) ? W[(size_t)(kt + 16 + wr) * N + nwc + 0] : 0.f;
                wv.y = (nwc + 1 < N) ? W[(size_t)(kt + 16 + wr) * N + nwc + 1] : 0.f;
                wv.z = (nwc + 2 < N) ? W[(size_t)(kt + 16 + wr) * N + nwc + 2] : 0.f;
                wv.w = (nwc + 3 < N) ? W[(size_t)(kt + 16 + wr) * N + nwc + 3] : 0.f;
            }
        }
        #pragma unroll
        for (int kk = 0; kk < 16; ++kk) {
            float4 xr4 = *(const float4*)&Xs[kk][tm * 4];
            float4 wr4 = *(const float4*)&Ws[kk][tn * 4];
            acc[0].x += xr4.x * wr4.x; acc[0].y += xr4.x * wr4.y;
            acc[0].z += xr4.x * wr4.z; acc[0].w += xr4.x * wr4.w;
            acc[1].x += xr4.y * wr4.x; acc[1].y += xr4.y * wr4.y;
            acc[1].z += xr4.y * wr4.z; acc[1].w += xr4.y * wr4.w;
            acc[2].x += xr4.z * wr4.x; acc[2].y += xr4.z * wr4.y;
            acc[2].z += xr4.z * wr4.z; acc[2].w += xr4.z * wr4.w;
            acc[3].x += xr4.w * wr4.x; acc[3].y += xr4.w * wr4.y;
            acc[3].z += xr4.w * wr4.z; acc[3].w += xr4.w * wr4.w;
        }
    }
    const int nbase = n0 + tn * 4;
    #pragma unroll
    for (int r = 0; r < 4; ++r) {
        int row = m0 + tm * 4 + r;
        float* pp = Pt + ((size_t)ks * M + row) * N + nbase;
        if (nbase + 3 < N) {
            *(float4*)pp = acc[r];
        } else {
            float vv[4] = { acc[r].x, acc[r].y, acc[r].z, acc[r].w };
            for (int c = 0; c < 4; ++c) if (nbase + c < N) pp[c] = vv[c];
        }
    }
}

__global__ __launch_bounds__(256) void fc_tile_kernel(const float* __restrict__ X,
        const float* __restrict__ W, float* __restrict__ Pt,
        int M, int K, int N, int Kc, int ntiles) {
    __shared__ __align__(16) float Xs[16][68];
    __shared__ __align__(16) float Ws[16][68];
    fc_tile_body(X, W, Pt, M, K, N, Kc, ntiles, blockIdx.x, Xs, Ws);
}

// Sum KS partial slices + bias (+ReLU). R6-verified. N % 4 == 0.
__global__ __launch_bounds__(256) void reduce_bias_kernel(const float* __restrict__ P,
        const float* __restrict__ bias, float* __restrict__ Y,
        int MN, int N, int KS, int do_relu) {
    int i = (blockIdx.x * 256 + threadIdx.x) * 4;
    if (i >= MN) return;
    float4 a = *(const float4*)(P + i);
    for (int s = 1; s < KS; ++s) {
        float4 b = *(const float4*)(P + (size_t)s * MN + i);
        a.x += b.x; a.y += b.y; a.z += b.z; a.w += b.w;
    }
    int n = i - (i / N) * N;
    float4 bb = *(const float4*)(bias + n);
    a.x += bb.x; a.y += bb.y; a.z += bb.z; a.w += bb.w;
    if (do_relu) {
        a.x = fmaxf(a.x, 0.f); a.y = fmaxf(a.y, 0.f);
        a.z = fmaxf(a.z, 0.f); a.w = fmaxf(a.w, 0.f);
    }
    *(float4*)(Y + i) = a;
}

// ---------------------------------------------------------------------------
// proj_body: projection GEMM task (TK=8, verified R6/R9/R10/R11). One task =
// (stage, 64x64 tile); 5 stages x 32 tiles = 160 tasks. Bias fused.
// ---------------------------------------------------------------------------
struct ProjParams {
    const float* W[5];
    const float* bp[5];
    const float* g[5];
    const float* be[5];
    int K[5];
    int poff[5];
};

__device__ void proj_body(const ProjParams& P, const float* __restrict__ pools,
        float* __restrict__ proj_out, int task,
        float (*Xs)[68], float (*Ws)[68]) {
    const int st  = task >> 5;
    const int bid = task & 31;
    const int K  = P.K[st];
    const float* X = pools + P.poff[st];
    const float* W = P.W[st];
    const int N = 512;
    int mt  = bid >> 3;
    int nt  = bid & 7;
    const int m0 = mt * 64, n0 = nt * 64;

    const int tid = threadIdx.x;
    const int tm = tid & 15;
    const int tn = tid >> 4;
    const int xa = tid >> 3, xb = tid & 7;
    const int wc = tid & 63, wb = tid >> 6;
    const int nw = n0 + wc;

    float4 acc[4];
    #pragma unroll
    for (int r = 0; r < 4; ++r) acc[r] = make_float4(0.f, 0.f, 0.f, 0.f);

    float x0, x1, w0v, w1v;
    x0  = X[(size_t)(m0 + xa) * K + xb];
    x1  = X[(size_t)(m0 + xa + 32) * K + xb];
    w0v = W[(size_t)wb * N + nw];
    w1v = W[(size_t)(wb + 4) * N + nw];

    for (int kt = 0; kt < K; kt += 8) {
        __syncthreads();
        Xs[xb][xa] = x0; Xs[xb][xa + 32] = x1;
        Ws[wb][wc] = w0v; Ws[wb + 4][wc] = w1v;
        __syncthreads();
        if (kt + 8 < K) {
            x0  = X[(size_t)(m0 + xa) * K + kt + 8 + xb];
            x1  = X[(size_t)(m0 + xa + 32) * K + kt + 8 + xb];
            w0v = W[(size_t)(kt + 8 + wb) * N + nw];
            w1v = W[(size_t)(kt + 8 + wb + 4) * N + nw];
        }
        #pragma unroll
        for (int kk = 0; kk < 8; ++kk) {
            float4 xr = *(const float4*)&Xs[kk][tm * 4];
            float4 wr = *(const float4*)&Ws[kk][tn * 4];
            acc[0].x += xr.x * wr.x; acc[0].y += xr.x * wr.y;
            acc[0].z += xr.x * wr.z; acc[0].w += xr.x * wr.w;
            acc[1].x += xr.y * wr.x; acc[1].y += xr.y * wr.y;
            acc[1].z += xr.y * wr.z; acc[1].w += xr.y * wr.w;
            acc[2].x += xr.z * wr.x; acc[2].y += xr.z * wr.y;
            acc[2].z += xr.z * wr.z; acc[2].w += xr.z * wr.w;
            acc[3].x += xr.w * wr.x; acc[3].y += xr.w * wr.y;
            acc[3].z += xr.w * wr.z; acc[3].w += xr.w * wr.w;
        }
    }
    const int nbase = n0 + tn * 4;
    float4 bb = *(const float4*)(P.bp[st] + nbase);
    float* op = proj_out + (size_t)st * 131072 + (size_t)(m0 + tm * 4) * N + nbase;
    #pragma unroll
    for (int r = 0; r < 4; ++r) {
        float4 v = acc[r];
        v.x += bb.x; v.y += bb.y; v.z += bb.z; v.w += bb.w;
        *(float4*)(op + (size_t)r * N) = v;
    }
}

// gate1 split-K (512 blocks) + proj (160 tasks) merged: independent work.
__global__ __launch_bounds__(256) void gate1_proj_kernel(
        const float* __restrict__ gate_in, const float* __restrict__ Wg1,
        float* __restrict__ slab, ProjParams P,
        const float* __restrict__ pools, float* __restrict__ proj_out) {
    __shared__ __align__(16) float Xs[16][68];
    __shared__ __align__(16) float Ws[16][68];
    if (blockIdx.x < 512) {
        fc_tile_body(gate_in, Wg1, slab, 256, 960, 1024, 128, 16,
                     blockIdx.x, Xs, Ws);
    } else {
        proj_body(P, pools, proj_out, blockIdx.x - 512,
                  (float(*)[68])Xs, (float(*)[68])Ws);
    }
}

// ---------------------------------------------------------------------------
// fc3 + mixln fused: dependency (topi/wsm) is batch-local, so one block per
// batch computes gate logits -> top2/softmax into LDS -> LayerNorm+GELU mix.
// 256 threads; mixln phase handles features f and f+256 per thread.
// jax.lax.top_k tie rule: lower index wins on equality (strict >).
// ---------------------------------------------------------------------------
__global__ __launch_bounds__(256) void fc3_mixln_kernel(
        const float* __restrict__ Xg, const float* __restrict__ Wg3,
        const float* __restrict__ bg3, ProjParams P,
        const float* __restrict__ proj_out, float* __restrict__ mix,
        float* __restrict__ out_gl, float* __restrict__ out_topi,
        float* __restrict__ out_w) {
    const int b    = blockIdx.x;
    const int tid  = threadIdx.x;
    const int lane = tid & 63;
    const int wv   = tid >> 6;
    __shared__ float red[4][5];
    __shared__ int   s_i0, s_i1;
    __shared__ float s_w0, s_w1;
    __shared__ float redS[4], redQ[4];
    __shared__ float s_mu, s_rstd;

    // ---- phase 1: gate fc3 + top2 + softmax ----
    {
        const float* x = Xg + (size_t)b * 512;
        float acc[5] = {0.f, 0.f, 0.f, 0.f, 0.f};
        for (int k = tid; k < 512; k += 256) {
            float xv = x[k];
            const float* wr = Wg3 + (size_t)k * 5;
            acc[0] += xv * wr[0]; acc[1] += xv * wr[1]; acc[2] += xv * wr[2];
            acc[3] += xv * wr[3]; acc[4] += xv * wr[4];
        }
        #pragma unroll
        for (int off = 32; off > 0; off >>= 1) {
            #pragma unroll
            for (int j = 0; j < 5; ++j) acc[j] += __shfl_down(acc[j], off, 64);
        }
        if (lane == 0) {
            #pragma unroll
            for (int j = 0; j < 5; ++j) red[wv][j] = acc[j];
        }
        __syncthreads();
        if (tid == 0) {
            float v[5];
            #pragma unroll
            for (int j = 0; j < 5; ++j)
                v[j] = ((red[0][j] + red[1][j]) + (red[2][j] + red[3][j])) + bg3[j];
            int i0 = 0;
            #pragma unroll
            for (int i = 1; i < 5; ++i) if (v[i] > v[i0]) i0 = i;
            int i1 = -1;
            #pragma unroll
            for (int i = 0; i < 5; ++i) {
                if (i == i0) continue;
                if (i1 < 0 || v[i] > v[i1]) i1 = i;
            }
            float e1 = __expf(v[i1] - v[i0]);
            float inv = 1.f / (1.f + e1);
            float w0 = inv, w1 = e1 * inv;
            s_i0 = i0; s_i1 = i1; s_w0 = w0; s_w1 = w1;
            #pragma unroll
            for (int j = 0; j < 5; ++j) out_gl[b * 5 + j] = v[j];
            out_topi[b * 2]     = (float)i0;
            out_topi[b * 2 + 1] = (float)i1;
            out_w[b * 2]     = w0;
            out_w[b * 2 + 1] = w1;
        }
    }
    __syncthreads();

    // ---- phase 2: mixln (f = tid and tid+256) ----
    float a0 = 0.f, a1 = 0.f;
    const int i0 = s_i0, i1 = s_i1;
    const float w0 = s_w0, w1 = s_w1;
    for (int j = 0; j < 2; ++j) {
        __syncthreads();                 // protect redS/redQ reuse
        const int st = j ? i1 : i0;
        const float w = j ? w1 : w0;
        const float* pp = proj_out + (size_t)st * 131072 + (size_t)b * 512;
        float h0 = pp[tid];
        float h1 = pp[tid + 256];
        float s = h0 + h1, q = h0 * h0 + h1 * h1;
        #pragma unroll
        for (int off = 32; off > 0; off >>= 1) {
            s += __shfl_down(s, off, 64);
            q += __shfl_down(q, off, 64);
        }
        if (lane == 0) { redS[wv] = s; redQ[wv] = q; }
        __syncthreads();
        if (tid == 0) {
            float ts = (redS[0] + redS[1]) + (redS[2] + redS[3]);
            float tq = (redQ[0] + redQ[1]) + (redQ[2] + redQ[3]);
            float mu  = ts * (1.f / 512.f);
            float var = tq * (1.f / 512.f) - mu * mu;
            s_mu   = mu;
            s_rstd = rsqrtf(var + 1e-5f);
        }
        __syncthreads();
        float mu = s_mu, rstd = s_rstd;
        float x0 = (h0 - mu) * rstd * P.g[st][tid] + P.be[st][tid];
        float x1 = (h1 - mu) * rstd * P.g[st][tid + 256] + P.be[st][tid + 256];
        a0 += w * (0.5f * x0 * (1.f + erff(x0 * 0.70710678118654752f)));
        a1 += w * (0.5f * x1 * (1.f + erff(x1 * 0.70710678118654752f)));
    }
    mix[(size_t)b * 512 + tid]       = a0;
    mix[(size_t)b * 512 + tid + 256] = a1;
}

// ---------------------------------------------------------------------------
extern "C" void kernel_launch(void* const* d_in, const int* in_sizes, int n_in,
                              void* d_out, int out_size, void* d_ws, size_t ws_size,
                              hipStream_t stream) {
    const int B = 256;

    const float* s1 = (const float*)d_in[0];
    const float* s2 = (const float*)d_in[1];
    const float* s3 = (const float*)d_in[2];
    const float* s4 = (const float*)d_in[3];
    const float* s5 = (const float*)d_in[4];
    const float* ff = (const float*)d_in[5];
    const float *Wp[5], *bp[5], *g[5], *be[5];
    for (int i = 0; i < 5; ++i) {
        Wp[i] = (const float*)d_in[6 + 4 * i];
        bp[i] = (const float*)d_in[7 + 4 * i];
        g[i]  = (const float*)d_in[8 + 4 * i];
        be[i] = (const float*)d_in[9 + 4 * i];
    }
    const float* Wg1 = (const float*)d_in[26]; const float* bg1 = (const float*)d_in[27];
    const float* Wg2 = (const float*)d_in[28]; const float* bg2 = (const float*)d_in[29];
    const float* Wg3 = (const float*)d_in[30]; const float* bg3 = (const float*)d_in[31];
    const float* Wc1 = (const float*)d_in[32]; const float* bc1 = (const float*)d_in[33];
    const float* Wc2 = (const float*)d_in[34]; const float* bc2 = (const float*)d_in[35];
    const float* Wc3 = (const float*)d_in[36]; const float* bc3 = (const float*)d_in[37];

    // ---- workspace layout (fp32 elements) ----
    float* ws = (float*)d_ws;
    const int Ks[5]   = {16, 24, 40, 80, 160};
    const int poff[5] = {0, 4096, 10240, 20480, 40960};
    float* pools    = ws;                                     // 81920
    float* gate_in  = ws + 81920;                             // 245760
    float* g1h      = ws + 327680;                            // 262144
    float* g2h      = ws + 589824;                            // 131072
    float* mix      = ws + 720896;                            // 131072
    float* proj_out = ws + 851968;                            // 655360
    float* c1h      = ws + 1507328;                           // 262144
    float* c2h      = ws + 1769472;                           // 131072
    float* slab     = ws + 1900544;                           // 2097152

    float* out      = (float*)d_out;
    float* out_gl   = out + 256000;
    float* out_topi = out + 257280;
    float* out_w    = out + 257792;

    // ---- 1) ALL pooling in one dispatch (NT loads) ----
    {
        PoolAll S;
        const float* srcs[4] = { s1, s2, s3, s4 };
        const int rls[4]  = { 112 * 112, 56 * 56, 28 * 28, 14 * 14 };
        const int rows[4] = { B * 16, B * 24, B * 40, B * 80 };
        int cum = 0;
        for (int i = 0; i < 4; ++i) {
            S.src[i] = srcs[i]; S.dst[i] = pools + poff[i]; S.n4[i] = rls[i] / 4;
            cum += rows[i]; S.cum[i] = cum; S.inv[i] = 1.f / rls[i];
        }
        S.nbb   = (cum * 64) / 256;           // 10240
        S.s5    = s5; S.ff = ff;
        S.dst5  = pools + poff[4]; S.dstf = gate_in;
        S.rows5 = B * 160;
        int small_blocks = (S.rows5 + B * 960) / 64;   // 4480
        pool_all_kernel<<<S.nbb + small_blocks, 256, 0, stream>>>(S);
    }

    ProjParams P;
    for (int i = 0; i < 5; ++i) {
        P.W[i] = Wp[i]; P.bp[i] = bp[i]; P.g[i] = g[i]; P.be[i] = be[i];
        P.K[i] = Ks[i]; P.poff[i] = poff[i];
    }

    // ---- 2) gate1 split-K (512 blocks) + proj (160 tasks), one dispatch ----
    gate1_proj_kernel<<<512 + 160, 256, 0, stream>>>(gate_in, Wg1, slab,
                                                     P, pools, proj_out);
    reduce_bias_kernel<<<(256 * 1024 / 4 + 255) / 256, 256, 0, stream>>>(
        slab, bg1, g1h, 256 * 1024, 1024, 8, 1);

    // ---- 3) gate2 split-K (KS=16, Kc=64) ----
    fc_tile_kernel<<<16 * 4 * 8, 256, 0, stream>>>(g1h, Wg2, slab,
                                                   256, 1024, 512, 64, 8);
    reduce_bias_kernel<<<(256 * 512 / 4 + 255) / 256, 256, 0, stream>>>(
        slab, bg2, g2h, 256 * 512, 512, 16, 1);

    // ---- 4) fc3 + top2 + mixln fused ----
    fc3_mixln_kernel<<<B, 256, 0, stream>>>(g2h, Wg3, bg3, P, proj_out, mix,
                                            out_gl, out_topi, out_w);

    // ---- 5) classifier MLP (split-K + reduce, R6-verified) ----
    fc_tile_kernel<<<8 * 4 * 16, 256, 0, stream>>>(mix, Wc1, slab,
                                                   256, 512, 1024, 64, 16);
    reduce_bias_kernel<<<(256 * 1024 / 4 + 255) / 256, 256, 0, stream>>>(
        slab, bc1, c1h, 256 * 1024, 1024, 8, 1);
    fc_tile_kernel<<<16 * 4 * 8, 256, 0, stream>>>(c1h, Wc2, slab,
                                                   256, 1024, 512, 64, 8);
    reduce_bias_kernel<<<(256 * 512 / 4 + 255) / 256, 256, 0, stream>>>(
        slab, bc2, c2h, 256 * 512, 512, 16, 1);
    fc_tile_kernel<<<8 * 4 * 16, 256, 0, stream>>>(c2h, Wc3, slab,
                                                   256, 512, 1000, 64, 16);
    reduce_bias_kernel<<<(256 * 1000 / 4 + 255) / 256, 256, 0, stream>>>(
        slab, bc3, out, 256 * 1000, 1000, 8, 0);
}

// Round 14
// 524.817 us; speedup vs baseline: 1.7472x; 1.0155x over previous
//
#include <hip/hip_runtime.h>
#include <math.h>

// All tensors fp32. B=256, F=512, H=1024, C=1000.

typedef float nt4 __attribute__((ext_vector_type(4)));

__device__ __forceinline__ float4 ntload(const float4* p) {
    nt4 v = __builtin_nontemporal_load((const nt4*)p);
    return make_float4(v.x, v.y, v.z, v.w);
}

// ---------------------------------------------------------------------------
// pool_all: ONE dispatch for all pooling; NT loads (R13-verified, at the
// ~3.4 TB/s read roofline). Do not touch.
// ---------------------------------------------------------------------------
struct PoolAll {
    const float* src[4];
    float*       dst[4];
    int n4[4];
    int cum[4];
    float inv[4];
    const float* s5;
    const float* ff;
    float*       dst5;
    float*       dstf;
    int nbb;
    int rows5;
};

__global__ __launch_bounds__(256) void pool_all_kernel(PoolAll S) {
    __shared__ float lds[64 * 49];
    if ((int)blockIdx.x < S.nbb) {
        int gid  = blockIdx.x * 256 + threadIdx.x;
        int wave = gid >> 6;
        int lane = gid & 63;
        if (wave >= S.cum[3]) return;
        int s = 0;
        #pragma unroll
        for (int i = 0; i < 3; ++i) if (wave >= S.cum[i]) s = i + 1;
        int row = wave - (s == 0 ? 0 : S.cum[s - 1]);
        const int n4 = S.n4[s];
        const float4* p4 = (const float4*)(S.src[s]) + (size_t)row * n4;
        float a0 = 0.f, a1 = 0.f, a2 = 0.f, a3 = 0.f;
        float a4 = 0.f, a5 = 0.f, a6 = 0.f, a7 = 0.f;
        int k = lane;
        for (; k + 448 < n4; k += 512) {
            float4 v0 = ntload(p4 + k);       float4 v1 = ntload(p4 + k + 64);
            float4 v2 = ntload(p4 + k + 128); float4 v3 = ntload(p4 + k + 192);
            float4 v4 = ntload(p4 + k + 256); float4 v5 = ntload(p4 + k + 320);
            float4 v6 = ntload(p4 + k + 384); float4 v7 = ntload(p4 + k + 448);
            a0 += (v0.x + v0.y) + (v0.z + v0.w);
            a1 += (v1.x + v1.y) + (v1.z + v1.w);
            a2 += (v2.x + v2.y) + (v2.z + v2.w);
            a3 += (v3.x + v3.y) + (v3.z + v3.w);
            a4 += (v4.x + v4.y) + (v4.z + v4.w);
            a5 += (v5.x + v5.y) + (v5.z + v5.w);
            a6 += (v6.x + v6.y) + (v6.z + v6.w);
            a7 += (v7.x + v7.y) + (v7.z + v7.w);
        }
        for (; k + 192 < n4; k += 256) {
            float4 v0 = ntload(p4 + k);       float4 v1 = ntload(p4 + k + 64);
            float4 v2 = ntload(p4 + k + 128); float4 v3 = ntload(p4 + k + 192);
            a0 += (v0.x + v0.y) + (v0.z + v0.w);
            a1 += (v1.x + v1.y) + (v1.z + v1.w);
            a2 += (v2.x + v2.y) + (v2.z + v2.w);
            a3 += (v3.x + v3.y) + (v3.z + v3.w);
        }
        for (; k < n4; k += 64) {
            float4 v = ntload(p4 + k);
            a0 += (v.x + v.y) + (v.z + v.w);
        }
        float acc = ((a0 + a1) + (a2 + a3)) + ((a4 + a5) + (a6 + a7));
        #pragma unroll
        for (int off = 32; off > 0; off >>= 1) acc += __shfl_down(acc, off, 64);
        if (lane == 0) S.dst[s][row] = acc * S.inv[s];
        return;
    }
    const int tid  = threadIdx.x;
    const int row0 = (blockIdx.x - S.nbb) * 64;
    const float* src;
    float* dst;
    int rbase;
    if (row0 < S.rows5) { src = S.s5; dst = S.dst5; rbase = row0; }
    else                { src = S.ff; dst = S.dstf; rbase = row0 - S.rows5; }
    const float4* p4 = (const float4*)(src + (size_t)rbase * 49);
    float4* l4 = (float4*)lds;
    float4 v0 = ntload(p4 + tid);
    float4 v1 = ntload(p4 + tid + 256);
    float4 v2 = ntload(p4 + tid + 512);
    float4 v3;
    const bool t3 = (tid < 784 - 768);
    if (t3) v3 = ntload(p4 + tid + 768);
    l4[tid]       = v0;
    l4[tid + 256] = v1;
    l4[tid + 512] = v2;
    if (t3) l4[tid + 768] = v3;
    __syncthreads();
    const int r  = tid >> 2;
    const int c0 = tid & 3;
    float s = 0.f;
    #pragma unroll
    for (int c = c0; c < 49; c += 4) s += lds[r * 49 + c];
    s += __shfl_down(s, 2, 64);
    s += __shfl_down(s, 1, 64);
    if (c0 == 0) dst[rbase + r] = s * (1.f / 49.f);
}

// ---------------------------------------------------------------------------
// fc_tile<XKS>: R6-verified LDS-tiled split-K SGEMM (tile 64x64, TK=16, 4x4
// micro, float4 staging, register prefetch).
//   XKS == 0: X is a plain [M][K] activation.
//   XKS == 8: X is a partial slab [8][M][K]; the X-stage computes
//             relu(xbias[k] + sum_s X[s][m][k]) — prev layer's reduce_bias
//             fused into staging (ascending-s order = reduce_bias order).
// Writes partials Pt[ks][M][N]. Grids stay 256-512 blocks (no KS=1).
// ---------------------------------------------------------------------------
template <int XKS>
__device__ void fc_tile_body(const float* __restrict__ X,
        const float* __restrict__ xbias, const float* __restrict__ W,
        float* __restrict__ Pt, int M, int K, int N, int Kc, int ntiles,
        int bid, float (*Xs)[68], float (*Ws)[68]) {
    const int tpk = 4 * ntiles;            // mtiles=4
    int ks  = bid / tpk;
    int rem = bid - ks * tpk;
    int mt  = rem / ntiles;
    int nt  = rem - mt * ntiles;
    const int m0 = mt * 64, n0 = nt * 64;
    const int k0 = ks * Kc;
    int k1 = k0 + Kc; if (k1 > K) k1 = K;

    const int tid = threadIdx.x;
    const int tm = tid & 15;
    const int tn = tid >> 4;
    const int xr = tid >> 2, xc = tid & 3;
    const int wr = tid >> 4, wc = tid & 15;
    const int nwc = n0 + wc * 4;
    const size_t MK = (size_t)M * K;
    const size_t xrow = (size_t)(m0 + xr) * K;

    float4 acc[4];
    #pragma unroll
    for (int r = 0; r < 4; ++r) acc[r] = make_float4(0.f, 0.f, 0.f, 0.f);

    const int NXV = (XKS > 0) ? XKS : 1;
    float4 xv[NXV];
    float4 wv;

    {
        const size_t xo = xrow + k0 + xc * 4;
        #pragma unroll
        for (int ss = 0; ss < NXV; ++ss)
            xv[ss] = *(const float4*)(X + (size_t)ss * MK + xo);
        if (nwc + 3 < N) {
            wv = *(const float4*)(W + (size_t)(k0 + wr) * N + nwc);
        } else {
            wv.x = (nwc + 0 < N) ? W[(size_t)(k0 + wr) * N + nwc + 0] : 0.f;
            wv.y = (nwc + 1 < N) ? W[(size_t)(k0 + wr) * N + nwc + 1] : 0.f;
            wv.z = (nwc + 2 < N) ? W[(size_t)(k0 + wr) * N + nwc + 2] : 0.f;
            wv.w = (nwc + 3 < N) ? W[(size_t)(k0 + wr) * N + nwc + 3] : 0.f;
        }
    }

    for (int kt = k0; kt < k1; kt += 16) {
        __syncthreads();
        float4 xs = xv[0];
        if (XKS > 0) {
            #pragma unroll
            for (int ss = 1; ss < NXV; ++ss) {
                xs.x += xv[ss].x; xs.y += xv[ss].y;
                xs.z += xv[ss].z; xs.w += xv[ss].w;
            }
            float4 xb = *(const float4*)(xbias + kt + xc * 4);
            xs.x = fmaxf(xs.x + xb.x, 0.f);
            xs.y = fmaxf(xs.y + xb.y, 0.f);
            xs.z = fmaxf(xs.z + xb.z, 0.f);
            xs.w = fmaxf(xs.w + xb.w, 0.f);
        }
        Xs[xc * 4 + 0][xr] = xs.x;
        Xs[xc * 4 + 1][xr] = xs.y;
        Xs[xc * 4 + 2][xr] = xs.z;
        Xs[xc * 4 + 3][xr] = xs.w;
        *(float4*)&Ws[wr][wc * 4] = wv;
        __syncthreads();
        if (kt + 16 < k1) {
            const size_t xo = xrow + kt + 16 + xc * 4;
            #pragma unroll
            for (int ss = 0; ss < NXV; ++ss)
                xv[ss] = *(const float4*)(X + (size_t)ss * MK + xo);
            if (nwc + 3 < N) {
                wv = *(const float4*)(W + (size_t)(kt + 16 + wr) * N + nwc);
            } else {
                wv.x = (nwc + 0 < N) ? W[(size_t)(kt + 16 + wr) * N + nwc + 0] : 0.f;
                wv.y = (nwc + 1 < N) ? W[(size_t)(kt + 16 + wr) * N + nwc + 1] : 0.f;
                wv.z = (nwc + 2 < N) ? W[(size_t)(kt + 16 + wr) * N + nwc + 2] : 0.f;
                wv.w = (nwc + 3 < N) ? W[(size_t)(kt + 16 + wr) * N + nwc + 3] : 0.f;
            }
        }
        #pragma unroll
        for (int kk = 0; kk < 16; ++kk) {
            float4 xr4 = *(const float4*)&Xs[kk][tm * 4];
            float4 wr4 = *(const float4*)&Ws[kk][tn * 4];
            acc[0].x += xr4.x * wr4.x; acc[0].y += xr4.x * wr4.y;
            acc[0].z += xr4.x * wr4.z; acc[0].w += xr4.x * wr4.w;
            acc[1].x += xr4.y * wr4.x; acc[1].y += xr4.y * wr4.y;
            acc[1].z += xr4.y * wr4.z; acc[1].w += xr4.y * wr4.w;
            acc[2].x += xr4.z * wr4.x; acc[2].y += xr4.z * wr4.y;
            acc[2].z += xr4.z * wr4.z; acc[2].w += xr4.z * wr4.w;
            acc[3].x += xr4.w * wr4.x; acc[3].y += xr4.w * wr4.y;
            acc[3].z += xr4.w * wr4.z; acc[3].w += xr4.w * wr4.w;
        }
    }
    const int nbase = n0 + tn * 4;
    #pragma unroll
    for (int r = 0; r < 4; ++r) {
        int row = m0 + tm * 4 + r;
        float* pp = Pt + ((size_t)ks * M + row) * N + nbase;
        if (nbase + 3 < N) {
            *(float4*)pp = acc[r];
        } else {
            float vv[4] = { acc[r].x, acc[r].y, acc[r].z, acc[r].w };
            for (int c = 0; c < 4; ++c) if (nbase + c < N) pp[c] = vv[c];
        }
    }
}

template <int XKS>
__global__ __launch_bounds__(256) void fc_tile_kernel(const float* __restrict__ X,
        const float* __restrict__ xbias, const float* __restrict__ W,
        float* __restrict__ Pt, int M, int K, int N, int Kc, int ntiles) {
    __shared__ __align__(16) float Xs[16][68];
    __shared__ __align__(16) float Ws[16][68];
    fc_tile_body<XKS>(X, xbias, W, Pt, M, K, N, Kc, ntiles, blockIdx.x, Xs, Ws);
}

// Sum KS partial slices + bias (+ReLU). R6-verified. N % 4 == 0.
__global__ __launch_bounds__(256) void reduce_bias_kernel(const float* __restrict__ P,
        const float* __restrict__ bias, float* __restrict__ Y,
        int MN, int N, int KS, int do_relu) {
    int i = (blockIdx.x * 256 + threadIdx.x) * 4;
    if (i >= MN) return;
    float4 a = *(const float4*)(P + i);
    for (int s = 1; s < KS; ++s) {
        float4 b = *(const float4*)(P + (size_t)s * MN + i);
        a.x += b.x; a.y += b.y; a.z += b.z; a.w += b.w;
    }
    int n = i - (i / N) * N;
    float4 bb = *(const float4*)(bias + n);
    a.x += bb.x; a.y += bb.y; a.z += bb.z; a.w += bb.w;
    if (do_relu) {
        a.x = fmaxf(a.x, 0.f); a.y = fmaxf(a.y, 0.f);
        a.z = fmaxf(a.z, 0.f); a.w = fmaxf(a.w, 0.f);
    }
    *(float4*)(Y + i) = a;
}

// ---------------------------------------------------------------------------
// proj_body: projection GEMM task (TK=8, verified R6..R13). Bias fused.
// ---------------------------------------------------------------------------
struct ProjParams {
    const float* W[5];
    const float* bp[5];
    const float* g[5];
    const float* be[5];
    int K[5];
    int poff[5];
};

__device__ void proj_body(const ProjParams& P, const float* __restrict__ pools,
        float* __restrict__ proj_out, int task,
        float (*Xs)[68], float (*Ws)[68]) {
    const int st  = task >> 5;
    const int bid = task & 31;
    const int K  = P.K[st];
    const float* X = pools + P.poff[st];
    const float* W = P.W[st];
    const int N = 512;
    int mt  = bid >> 3;
    int nt  = bid & 7;
    const int m0 = mt * 64, n0 = nt * 64;

    const int tid = threadIdx.x;
    const int tm = tid & 15;
    const int tn = tid >> 4;
    const int xa = tid >> 3, xb = tid & 7;
    const int wc = tid & 63, wb = tid >> 6;
    const int nw = n0 + wc;

    float4 acc[4];
    #pragma unroll
    for (int r = 0; r < 4; ++r) acc[r] = make_float4(0.f, 0.f, 0.f, 0.f);

    float x0, x1, w0v, w1v;
    x0  = X[(size_t)(m0 + xa) * K + xb];
    x1  = X[(size_t)(m0 + xa + 32) * K + xb];
    w0v = W[(size_t)wb * N + nw];
    w1v = W[(size_t)(wb + 4) * N + nw];

    for (int kt = 0; kt < K; kt += 8) {
        __syncthreads();
        Xs[xb][xa] = x0; Xs[xb][xa + 32] = x1;
        Ws[wb][wc] = w0v; Ws[wb + 4][wc] = w1v;
        __syncthreads();
        if (kt + 8 < K) {
            x0  = X[(size_t)(m0 + xa) * K + kt + 8 + xb];
            x1  = X[(size_t)(m0 + xa + 32) * K + kt + 8 + xb];
            w0v = W[(size_t)(kt + 8 + wb) * N + nw];
            w1v = W[(size_t)(kt + 8 + wb + 4) * N + nw];
        }
        #pragma unroll
        for (int kk = 0; kk < 8; ++kk) {
            float4 xr = *(const float4*)&Xs[kk][tm * 4];
            float4 wr = *(const float4*)&Ws[kk][tn * 4];
            acc[0].x += xr.x * wr.x; acc[0].y += xr.x * wr.y;
            acc[0].z += xr.x * wr.z; acc[0].w += xr.x * wr.w;
            acc[1].x += xr.y * wr.x; acc[1].y += xr.y * wr.y;
            acc[1].z += xr.y * wr.z; acc[1].w += xr.y * wr.w;
            acc[2].x += xr.z * wr.x; acc[2].y += xr.z * wr.y;
            acc[2].z += xr.z * wr.z; acc[2].w += xr.z * wr.w;
            acc[3].x += xr.w * wr.x; acc[3].y += xr.w * wr.y;
            acc[3].z += xr.w * wr.z; acc[3].w += xr.w * wr.w;
        }
    }
    const int nbase = n0 + tn * 4;
    float4 bb = *(const float4*)(P.bp[st] + nbase);
    float* op = proj_out + (size_t)st * 131072 + (size_t)(m0 + tm * 4) * N + nbase;
    #pragma unroll
    for (int r = 0; r < 4; ++r) {
        float4 v = acc[r];
        v.x += bb.x; v.y += bb.y; v.z += bb.z; v.w += bb.w;
        *(float4*)(op + (size_t)r * N) = v;
    }
}

// gate1 split-K (512 blocks) + proj (160 tasks) merged: independent work.
__global__ __launch_bounds__(256) void gate1_proj_kernel(
        const float* __restrict__ gate_in, const float* __restrict__ Wg1,
        float* __restrict__ slab, ProjParams P,
        const float* __restrict__ pools, float* __restrict__ proj_out) {
    __shared__ __align__(16) float Xs[16][68];
    __shared__ __align__(16) float Ws[16][68];
    if (blockIdx.x < 512) {
        fc_tile_body<0>(gate_in, nullptr, Wg1, slab, 256, 960, 1024, 128, 16,
                        blockIdx.x, Xs, Ws);
    } else {
        proj_body(P, pools, proj_out, blockIdx.x - 512,
                  (float(*)[68])Xs, (float(*)[68])Ws);
    }
}

// ---------------------------------------------------------------------------
// fc3 + mixln fused; fc3 input = gate2's 16 partial slices, reduced inline
// (ascending s + bg2 + relu — identical order to reduce_bias).
// ---------------------------------------------------------------------------
__global__ __launch_bounds__(256) void fc3_mixln_kernel(
        const float* __restrict__ Xp, const float* __restrict__ bg2,
        const float* __restrict__ Wg3, const float* __restrict__ bg3,
        ProjParams P, const float* __restrict__ proj_out,
        float* __restrict__ mix, float* __restrict__ out_gl,
        float* __restrict__ out_topi, float* __restrict__ out_w) {
    const int b    = blockIdx.x;
    const int tid  = threadIdx.x;
    const int lane = tid & 63;
    const int wv   = tid >> 6;
    __shared__ float red[4][5];
    __shared__ int   s_i0, s_i1;
    __shared__ float s_w0, s_w1;
    __shared__ float redS[4], redQ[4];
    __shared__ float s_mu, s_rstd;

    // ---- phase 1: gate fc3 (inline 16-slice reduce) + top2 + softmax ----
    {
        const size_t MK = (size_t)256 * 512;
        float acc[5] = {0.f, 0.f, 0.f, 0.f, 0.f};
        for (int k = tid; k < 512; k += 256) {
            float v = Xp[(size_t)b * 512 + k];
            #pragma unroll
            for (int s = 1; s < 16; ++s)
                v += Xp[(size_t)s * MK + (size_t)b * 512 + k];
            float xv = fmaxf(v + bg2[k], 0.f);
            const float* wr = Wg3 + (size_t)k * 5;
            acc[0] += xv * wr[0]; acc[1] += xv * wr[1]; acc[2] += xv * wr[2];
            acc[3] += xv * wr[3]; acc[4] += xv * wr[4];
        }
        #pragma unroll
        for (int off = 32; off > 0; off >>= 1) {
            #pragma unroll
            for (int j = 0; j < 5; ++j) acc[j] += __shfl_down(acc[j], off, 64);
        }
        if (lane == 0) {
            #pragma unroll
            for (int j = 0; j < 5; ++j) red[wv][j] = acc[j];
        }
        __syncthreads();
        if (tid == 0) {
            float v[5];
            #pragma unroll
            for (int j = 0; j < 5; ++j)
                v[j] = ((red[0][j] + red[1][j]) + (red[2][j] + red[3][j])) + bg3[j];
            int i0 = 0;
            #pragma unroll
            for (int i = 1; i < 5; ++i) if (v[i] > v[i0]) i0 = i;
            int i1 = -1;
            #pragma unroll
            for (int i = 0; i < 5; ++i) {
                if (i == i0) continue;
                if (i1 < 0 || v[i] > v[i1]) i1 = i;
            }
            float e1 = __expf(v[i1] - v[i0]);
            float inv = 1.f / (1.f + e1);
            float w0 = inv, w1 = e1 * inv;
            s_i0 = i0; s_i1 = i1; s_w0 = w0; s_w1 = w1;
            #pragma unroll
            for (int j = 0; j < 5; ++j) out_gl[b * 5 + j] = v[j];
            out_topi[b * 2]     = (float)i0;
            out_topi[b * 2 + 1] = (float)i1;
            out_w[b * 2]     = w0;
            out_w[b * 2 + 1] = w1;
        }
    }
    __syncthreads();

    // ---- phase 2: mixln (f = tid and tid+256) ----
    float a0 = 0.f, a1 = 0.f;
    const int i0 = s_i0, i1 = s_i1;
    const float w0 = s_w0, w1 = s_w1;
    for (int j = 0; j < 2; ++j) {
        __syncthreads();
        const int st = j ? i1 : i0;
        const float w = j ? w1 : w0;
        const float* pp = proj_out + (size_t)st * 131072 + (size_t)b * 512;
        float h0 = pp[tid];
        float h1 = pp[tid + 256];
        float s = h0 + h1, q = h0 * h0 + h1 * h1;
        #pragma unroll
        for (int off = 32; off > 0; off >>= 1) {
            s += __shfl_down(s, off, 64);
            q += __shfl_down(q, off, 64);
        }
        if (lane == 0) { redS[wv] = s; redQ[wv] = q; }
        __syncthreads();
        if (tid == 0) {
            float ts = (redS[0] + redS[1]) + (redS[2] + redS[3]);
            float tq = (redQ[0] + redQ[1]) + (redQ[2] + redQ[3]);
            float mu  = ts * (1.f / 512.f);
            float var = tq * (1.f / 512.f) - mu * mu;
            s_mu   = mu;
            s_rstd = rsqrtf(var + 1e-5f);
        }
        __syncthreads();
        float mu = s_mu, rstd = s_rstd;
        float x0 = (h0 - mu) * rstd * P.g[st][tid] + P.be[st][tid];
        float x1 = (h1 - mu) * rstd * P.g[st][tid + 256] + P.be[st][tid + 256];
        a0 += w * (0.5f * x0 * (1.f + erff(x0 * 0.70710678118654752f)));
        a1 += w * (0.5f * x1 * (1.f + erff(x1 * 0.70710678118654752f)));
    }
    mix[(size_t)b * 512 + tid]       = a0;
    mix[(size_t)b * 512 + tid + 256] = a1;
}

// ---------------------------------------------------------------------------
extern "C" void kernel_launch(void* const* d_in, const int* in_sizes, int n_in,
                              void* d_out, int out_size, void* d_ws, size_t ws_size,
                              hipStream_t stream) {
    const int B = 256;

    const float* s1 = (const float*)d_in[0];
    const float* s2 = (const float*)d_in[1];
    const float* s3 = (const float*)d_in[2];
    const float* s4 = (const float*)d_in[3];
    const float* s5 = (const float*)d_in[4];
    const float* ff = (const float*)d_in[5];
    const float *Wp[5], *bp[5], *g[5], *be[5];
    for (int i = 0; i < 5; ++i) {
        Wp[i] = (const float*)d_in[6 + 4 * i];
        bp[i] = (const float*)d_in[7 + 4 * i];
        g[i]  = (const float*)d_in[8 + 4 * i];
        be[i] = (const float*)d_in[9 + 4 * i];
    }
    const float* Wg1 = (const float*)d_in[26]; const float* bg1 = (const float*)d_in[27];
    const float* Wg2 = (const float*)d_in[28]; const float* bg2 = (const float*)d_in[29];
    const float* Wg3 = (const float*)d_in[30]; const float* bg3 = (const float*)d_in[31];
    const float* Wc1 = (const float*)d_in[32]; const float* bc1 = (const float*)d_in[33];
    const float* Wc2 = (const float*)d_in[34]; const float* bc2 = (const float*)d_in[35];
    const float* Wc3 = (const float*)d_in[36]; const float* bc3 = (const float*)d_in[37];

    // ---- workspace layout (fp32 elements) ----
    float* ws = (float*)d_ws;
    const int Ks[5]   = {16, 24, 40, 80, 160};
    const int poff[5] = {0, 4096, 10240, 20480, 40960};
    float* pools    = ws;                                     // 81920
    float* gate_in  = ws + 81920;                             // 245760
    float* mix      = ws + 327680;                            // 131072
    float* proj_out = ws + 458752;                            // 655360
    float* slabA    = ws + 1114112;                           // 2097152
    float* slabB    = ws + 3211264;                           // 2097152

    float* out      = (float*)d_out;
    float* out_gl   = out + 256000;
    float* out_topi = out + 257280;
    float* out_w    = out + 257792;

    // ---- 1) ALL pooling in one dispatch (NT loads) ----
    {
        PoolAll S;
        const float* srcs[4] = { s1, s2, s3, s4 };
        const int rls[4]  = { 112 * 112, 56 * 56, 28 * 28, 14 * 14 };
        const int rows[4] = { B * 16, B * 24, B * 40, B * 80 };
        int cum = 0;
        for (int i = 0; i < 4; ++i) {
            S.src[i] = srcs[i]; S.dst[i] = pools + poff[i]; S.n4[i] = rls[i] / 4;
            cum += rows[i]; S.cum[i] = cum; S.inv[i] = 1.f / rls[i];
        }
        S.nbb   = (cum * 64) / 256;           // 10240
        S.s5    = s5; S.ff = ff;
        S.dst5  = pools + poff[4]; S.dstf = gate_in;
        S.rows5 = B * 160;
        int small_blocks = (S.rows5 + B * 960) / 64;   // 4480
        pool_all_kernel<<<S.nbb + small_blocks, 256, 0, stream>>>(S);
    }

    ProjParams P;
    for (int i = 0; i < 5; ++i) {
        P.W[i] = Wp[i]; P.bp[i] = bp[i]; P.g[i] = g[i]; P.be[i] = be[i];
        P.K[i] = Ks[i]; P.poff[i] = poff[i];
    }

    // ---- 2) gate1 split-K (KS=8, 512 blocks) + proj, one dispatch -> slabA
    gate1_proj_kernel<<<512 + 160, 256, 0, stream>>>(gate_in, Wg1, slabA,
                                                     P, pools, proj_out);
    // ---- 3) gate2: XKS=8 fused reduce(bg1,relu), KS=16 (512 blocks) -> slabB
    fc_tile_kernel<8><<<16 * 4 * 8, 256, 0, stream>>>(
        slabA, bg1, Wg2, slabB, 256, 1024, 512, 64, 8);
    // ---- 4) fc3 (inline 16-slice reduce + bg2 + relu) + top2 + mixln ----
    fc3_mixln_kernel<<<B, 256, 0, stream>>>(slabB, bg2, Wg3, bg3, P, proj_out,
                                            mix, out_gl, out_topi, out_w);
    // ---- 5) cls1: KS=8 (512 blocks) -> slabA
    fc_tile_kernel<0><<<8 * 4 * 16, 256, 0, stream>>>(
        mix, nullptr, Wc1, slabA, 256, 512, 1024, 64, 16);
    // ---- 6) cls2: XKS=8 fused reduce(bc1,relu), KS=8 Kc=128 (256 blocks) -> slabB
    fc_tile_kernel<8><<<8 * 4 * 8, 256, 0, stream>>>(
        slabA, bc1, Wc2, slabB, 256, 1024, 512, 128, 8);
    // ---- 7) cls3: XKS=8 fused reduce(bc2,relu), KS=8 (512 blocks) -> slabA
    fc_tile_kernel<8><<<8 * 4 * 16, 256, 0, stream>>>(
        slabB, bc2, Wc3, slabA, 256, 512, 1000, 64, 16);
    // ---- 8) final reduce + bc3 -> out logits
    reduce_bias_kernel<<<(256 * 1000 / 4 + 255) / 256, 256, 0, stream>>>(
        slabA, bc3, out, 256 * 1000, 1000, 8, 0);
}